// Round 1
// baseline (3878.786 us; speedup 1.0000x reference)
//
#include <hip/hip_runtime.h>
#include <hip/hip_bf16.h>
#include <stdint.h>

// ---------------- constants ----------------
#define N_NODES   20000
#define MP        20096          // padded to 157*128
#define N_TYPES   5
#define N_EDGES   64000
#define IN_C      2048
#define HID_C     1024
#define OUT_C     512

typedef __attribute__((ext_vector_type(8))) short short8;   // 8 bf16 (4 VGPR)
typedef __attribute__((ext_vector_type(4))) float f32x4;

// ---------------- helpers ----------------
__device__ __forceinline__ unsigned short f2b(float f) {
  union { float f; uint32_t u; } c; c.f = f;
  uint32_t u = c.u;
  u += 0x7FFFu + ((u >> 16) & 1u);          // RNE
  return (unsigned short)(u >> 16);
}
__device__ __forceinline__ float b2f(unsigned short h) {
  union { uint32_t u; float f; } c; c.u = ((uint32_t)h) << 16; return c.f;
}
__device__ __forceinline__ void gload_lds16(const void* g, void* l) {
  __builtin_amdgcn_global_load_lds((__attribute__((address_space(1))) void*)g,
                                   (__attribute__((address_space(3))) void*)l,
                                   16, 0, 0);
}

// ---------------- small prep kernels ----------------
__global__ __launch_bounds__(64) void softmax5_k(const float* __restrict__ attn, float* __restrict__ w) {
  if (threadIdx.x == 0) {
    float m = attn[0];
    for (int i = 1; i < N_TYPES; ++i) m = fmaxf(m, attn[i]);
    float e[N_TYPES], s = 0.f;
    for (int i = 0; i < N_TYPES; ++i) { e[i] = expf(attn[i] - m); s += e[i]; }
    for (int i = 0; i < N_TYPES; ++i) w[i] = e[i] / s;
  }
}

__global__ __launch_bounds__(256) void zero_int_k(int* __restrict__ p, int n) {
  int i = blockIdx.x * 256 + threadIdx.x;
  if (i < n) p[i] = 0;
}

__global__ __launch_bounds__(256) void hist_k(const int* __restrict__ edges, int* __restrict__ deg) {
  int t = blockIdx.x * 256 + threadIdx.x;
  if (t < N_TYPES * N_EDGES) {
    int ty = t / N_EDGES, e = t - ty * N_EDGES;
    int dst = edges[ty * 2 * N_EDGES + N_EDGES + e];
    atomicAdd(&deg[ty * N_NODES + dst], 1);
  }
}

__global__ __launch_bounds__(256) void scan_k(const int* __restrict__ deg, int* __restrict__ rowptr,
                                              int* __restrict__ cursor) {
  int ty = blockIdx.x;
  const int* d = deg + ty * N_NODES;
  int* rp = rowptr + ty * (N_NODES + 1);
  int* cu = cursor + ty * N_NODES;
  __shared__ int sh[256];
  __shared__ int s_carry;
  int tid = threadIdx.x;
  if (tid == 0) s_carry = 0;
  __syncthreads();
  for (int base = 0; base < N_NODES; base += 256) {
    int i = base + tid;
    int v = (i < N_NODES) ? d[i] : 0;
    sh[tid] = v; __syncthreads();
    for (int off = 1; off < 256; off <<= 1) {
      int t2 = (tid >= off) ? sh[tid - off] : 0;
      __syncthreads();
      sh[tid] += t2;
      __syncthreads();
    }
    int incl = sh[tid];
    int c = s_carry;
    if (i < N_NODES) { rp[i] = c + incl - v; cu[i] = c + incl - v; }
    __syncthreads();
    if (tid == 255) s_carry = c + incl;
    __syncthreads();
  }
  if (tid == 0) rp[N_NODES] = s_carry;
}

__global__ __launch_bounds__(256) void scatter_k(const int* __restrict__ edges, int* __restrict__ cursor,
                                                 int* __restrict__ colidx) {
  int t = blockIdx.x * 256 + threadIdx.x;
  if (t < N_TYPES * N_EDGES) {
    int ty = t / N_EDGES, e = t - ty * N_EDGES;
    int src = edges[ty * 2 * N_EDGES + e];
    int dst = edges[ty * 2 * N_EDGES + N_EDGES + e];
    int pos = atomicAdd(&cursor[ty * N_NODES + dst], 1);
    colidx[ty * N_EDGES + pos] = src;
  }
}

// x fp32 [20000,2048] -> bf16 [20096,2048], pad rows zero
__global__ __launch_bounds__(256) void cvt_x_k(const float* __restrict__ x, unsigned short* __restrict__ xb) {
  int i = blockIdx.x * 256 + threadIdx.x;     // [0, 20096*512)
  int row = i >> 9;
  int c4 = (i & 511) << 2;
  ushort4 o;
  if (row < N_NODES) {
    float4 v = *(const float4*)(x + (size_t)row * IN_C + c4);
    o.x = f2b(v.x); o.y = f2b(v.y); o.z = f2b(v.z); o.w = f2b(v.w);
  } else { o.x = 0; o.y = 0; o.z = 0; o.w = 0; }
  *(ushort4*)(xb + (size_t)row * IN_C + c4) = o;
}

__global__ __launch_bounds__(256) void cvt_w_k(const float* __restrict__ s, unsigned short* __restrict__ d, int n4) {
  int i = blockIdx.x * 256 + threadIdx.x;
  if (i < n4) {
    float4 v = ((const float4*)s)[i];
    ushort4 o; o.x = f2b(v.x); o.y = f2b(v.y); o.z = f2b(v.z); o.w = f2b(v.w);
    ((ushort4*)d)[i] = o;
  }
}

// ---------------- CSR mean-gather: Agg[n] = mean_{src in N(n)} H[src], bf16 in/out, fp32 accum ----------------
template<int C>
__global__ __launch_bounds__(256) void gather_k(const unsigned short* __restrict__ H,
                                                unsigned short* __restrict__ Agg,
                                                const int* __restrict__ rowptr,
                                                const int* __restrict__ colidx) {
  constexpr int V = C / 256;                 // 8 (C=2048) or 4 (C=1024)
  int node = blockIdx.x;
  int tid = threadIdx.x;
  float acc[V];
#pragma unroll
  for (int j = 0; j < V; ++j) acc[j] = 0.f;
  if (node < N_NODES) {
    int beg = rowptr[node], end = rowptr[node + 1];
    for (int e = beg; e < end; ++e) {
      int src = colidx[e];
      const unsigned short* p = H + (size_t)src * C + tid * V;
#pragma unroll
      for (int j = 0; j < V; j += 4) {
        ushort4 u = *(const ushort4*)(p + j);
        acc[j + 0] += b2f(u.x); acc[j + 1] += b2f(u.y);
        acc[j + 2] += b2f(u.z); acc[j + 3] += b2f(u.w);
      }
    }
    int dg = end - beg;
    float inv = dg > 0 ? 1.f / (float)dg : 0.f;
#pragma unroll
    for (int j = 0; j < V; ++j) acc[j] *= inv;
  }
  unsigned short* q = Agg + (size_t)node * C + tid * V;
#pragma unroll
  for (int j = 0; j < V; j += 4) {
    ushort4 o; o.x = f2b(acc[j]); o.y = f2b(acc[j + 1]); o.z = f2b(acc[j + 2]); o.w = f2b(acc[j + 3]);
    *(ushort4*)(q + j) = o;
  }
}

// ---------------- fused dual GEMM: C[M,N] = A1@W1^T + A2@W2^T + bias  (W row-major [N,K]) ----------------
// 128x128 tile, 4 waves (each 64x64 = 4x4 frags of 16x16), BK=32, global_load_lds staging.
// MODE 0: Hout(bf16, stride N, MP rows, pad rows zeroed), optional RELU.
// MODE 1: Cout fp32 [20000,N]: type 0 writes w*val, others += w*val.
template<int NSIZE, int KSIZE, bool RELU, int MODE>
__global__ __launch_bounds__(256) void gemm_dual_k(const unsigned short* __restrict__ A1,
                                                   const unsigned short* __restrict__ W1,
                                                   const unsigned short* __restrict__ A2,
                                                   const unsigned short* __restrict__ W2,
                                                   const float* __restrict__ bias,
                                                   unsigned short* __restrict__ Hout,
                                                   float* __restrict__ Cout,
                                                   const float* __restrict__ wsm, int itype) {
  __shared__ unsigned short As[128 * 32];
  __shared__ unsigned short Bs[128 * 32];
  const int tid = threadIdx.x;
  const int lane = tid & 63;
  const int wave = tid >> 6;
  const int wm = wave >> 1, wn = wave & 1;
  const int row0 = blockIdx.x * 128;
  const int col0 = blockIdx.y * 128;

  f32x4 acc[4][4];
#pragma unroll
  for (int m = 0; m < 4; ++m)
#pragma unroll
    for (int n = 0; n < 4; ++n) acc[m][n] = (f32x4)(0.f);

  const int lrow = lane >> 2;          // staging: row within 16-row group
  const int lkb = (lane & 3) * 8;      // staging: k element offset
  const int frow = lane & 15;          // fragment row/col
  const int fk = (lane >> 4) * 8;      // fragment k offset

  for (int seg = 0; seg < 2; ++seg) {
    const unsigned short* A = seg ? A2 : A1;
    const unsigned short* W = seg ? W2 : W1;
    for (int kb = 0; kb < KSIZE; kb += 32) {
      __syncthreads();
#pragma unroll
      for (int j = 0; j < 2; ++j) {
        int rs = (wave + 4 * j) * 16;
        gload_lds16(A + (size_t)(row0 + rs + lrow) * KSIZE + kb + lkb, &As[rs * 32]);
        gload_lds16(W + (size_t)(col0 + rs + lrow) * KSIZE + kb + lkb, &Bs[rs * 32]);
      }
      __syncthreads();
      short8 af[4], bfr[4];
#pragma unroll
      for (int m = 0; m < 4; ++m)
        af[m] = *(const short8*)&As[(wm * 64 + m * 16 + frow) * 32 + fk];
#pragma unroll
      for (int n = 0; n < 4; ++n)
        bfr[n] = *(const short8*)&Bs[(wn * 64 + n * 16 + frow) * 32 + fk];
#pragma unroll
      for (int m = 0; m < 4; ++m)
#pragma unroll
        for (int n = 0; n < 4; ++n)
          acc[m][n] = __builtin_amdgcn_mfma_f32_16x16x32_bf16(af[m], bfr[n], acc[m][n], 0, 0, 0);
    }
  }

  // epilogue: D layout col=lane&15, row=(lane>>4)*4+reg  [verified gfx950 mapping]
  const int erow = (lane >> 4) * 4;
  const int ecol = lane & 15;
  float wgt = (MODE == 1) ? wsm[itype] : 0.f;
#pragma unroll
  for (int m = 0; m < 4; ++m) {
#pragma unroll
    for (int n = 0; n < 4; ++n) {
      int gcol = col0 + wn * 64 + n * 16 + ecol;
      float bv = bias[gcol];
#pragma unroll
      for (int r = 0; r < 4; ++r) {
        int grow = row0 + wm * 64 + m * 16 + erow + r;
        float v = acc[m][n][r] + bv;
        if (RELU) v = fmaxf(v, 0.f);
        if (MODE == 0) {
          if (grow >= N_NODES) v = 0.f;   // keep pad rows zero
          Hout[(size_t)grow * NSIZE + gcol] = f2b(v);
        } else {
          if (grow < N_NODES) {
            size_t o = (size_t)grow * NSIZE + gcol;
            float ov = wgt * v;
            if (itype == 0) Cout[o] = ov; else Cout[o] += ov;
          }
        }
      }
    }
  }
}

// ---------------- final row L2 normalize (in place on d_out) ----------------
__global__ __launch_bounds__(128) void l2norm_k(float* __restrict__ out) {
  int row = blockIdx.x;
  int tid = threadIdx.x;                 // 128 threads * float4 = 512 cols
  float4 v = ((float4*)(out + (size_t)row * OUT_C))[tid];
  float ss = v.x * v.x + v.y * v.y + v.z * v.z + v.w * v.w;
  for (int off = 32; off > 0; off >>= 1) ss += __shfl_down(ss, off);
  __shared__ float s2[2];
  if ((tid & 63) == 0) s2[tid >> 6] = ss;
  __syncthreads();
  float tot = s2[0] + s2[1];
  float inv = 1.f / fmaxf(sqrtf(tot), 1e-12f);
  v.x *= inv; v.y *= inv; v.z *= inv; v.w *= inv;
  ((float4*)(out + (size_t)row * OUT_C))[tid] = v;
}

// ---------------- launch ----------------
extern "C" void kernel_launch(void* const* d_in, const int* in_sizes, int n_in,
                              void* d_out, int out_size, void* d_ws, size_t ws_size,
                              hipStream_t stream) {
  const float* x    = (const float*)d_in[0];
  const int*   edges = (const int*)d_in[1];
  const float* Wl1 = (const float*)d_in[2];
  const float* bl1 = (const float*)d_in[3];
  const float* Wr1 = (const float*)d_in[4];
  const float* Wl2 = (const float*)d_in[5];
  const float* bl2 = (const float*)d_in[6];
  const float* Wr2 = (const float*)d_in[7];
  const float* Wl3 = (const float*)d_in[8];
  const float* bl3 = (const float*)d_in[9];
  const float* Wr3 = (const float*)d_in[10];
  const float* attn = (const float*)d_in[11];
  float* out = (float*)d_out;

  char* ws = (char*)d_ws;
  size_t off = 0;
  auto alloc = [&](size_t bytes) -> char* {
    char* p = ws + off;
    off = (off + bytes + 255) & ~(size_t)255;
    return p;
  };
  float* wsm   = (float*)alloc(N_TYPES * 4);
  int* deg     = (int*)alloc((size_t)N_TYPES * N_NODES * 4);
  int* rowptr  = (int*)alloc((size_t)N_TYPES * (N_NODES + 1) * 4);
  int* cursor  = (int*)alloc((size_t)N_TYPES * N_NODES * 4);
  int* colidx  = (int*)alloc((size_t)N_TYPES * N_EDGES * 4);
  unsigned short* xb   = (unsigned short*)alloc((size_t)MP * IN_C * 2);
  unsigned short* agg  = (unsigned short*)alloc((size_t)MP * IN_C * 2);
  unsigned short* h1   = (unsigned short*)alloc((size_t)MP * HID_C * 2);
  unsigned short* h2   = (unsigned short*)alloc((size_t)MP * HID_C * 2);
  unsigned short* wl1b = (unsigned short*)alloc((size_t)N_TYPES * HID_C * IN_C * 2);
  unsigned short* wr1b = (unsigned short*)alloc((size_t)N_TYPES * HID_C * IN_C * 2);
  unsigned short* wl2b = (unsigned short*)alloc((size_t)N_TYPES * HID_C * HID_C * 2);
  unsigned short* wr2b = (unsigned short*)alloc((size_t)N_TYPES * HID_C * HID_C * 2);
  unsigned short* wl3b = (unsigned short*)alloc((size_t)N_TYPES * OUT_C * HID_C * 2);
  unsigned short* wr3b = (unsigned short*)alloc((size_t)N_TYPES * OUT_C * HID_C * 2);

  // prep
  softmax5_k<<<1, 64, 0, stream>>>(attn, wsm);
  zero_int_k<<<(N_TYPES * N_NODES + 255) / 256, 256, 0, stream>>>(deg, N_TYPES * N_NODES);
  hist_k<<<(N_TYPES * N_EDGES + 255) / 256, 256, 0, stream>>>(edges, deg);
  scan_k<<<N_TYPES, 256, 0, stream>>>(deg, rowptr, cursor);
  scatter_k<<<(N_TYPES * N_EDGES + 255) / 256, 256, 0, stream>>>(edges, cursor, colidx);

  cvt_x_k<<<(MP * IN_C / 4 + 255) / 256, 256, 0, stream>>>(x, xb);
  {
    int n4;
    n4 = N_TYPES * HID_C * IN_C / 4;
    cvt_w_k<<<(n4 + 255) / 256, 256, 0, stream>>>(Wl1, wl1b, n4);
    cvt_w_k<<<(n4 + 255) / 256, 256, 0, stream>>>(Wr1, wr1b, n4);
    n4 = N_TYPES * HID_C * HID_C / 4;
    cvt_w_k<<<(n4 + 255) / 256, 256, 0, stream>>>(Wl2, wl2b, n4);
    cvt_w_k<<<(n4 + 255) / 256, 256, 0, stream>>>(Wr2, wr2b, n4);
    n4 = N_TYPES * OUT_C * HID_C / 4;
    cvt_w_k<<<(n4 + 255) / 256, 256, 0, stream>>>(Wl3, wl3b, n4);
    cvt_w_k<<<(n4 + 255) / 256, 256, 0, stream>>>(Wr3, wr3b, n4);
  }

  for (int i = 0; i < N_TYPES; ++i) {
    const int* rp = rowptr + i * (N_NODES + 1);
    const int* ci = colidx + i * N_EDGES;
    // layer 1
    gather_k<IN_C><<<MP, 256, 0, stream>>>(xb, agg, rp, ci);
    gemm_dual_k<HID_C, IN_C, true, 0><<<dim3(MP / 128, HID_C / 128), 256, 0, stream>>>(
        agg, wl1b + (size_t)i * HID_C * IN_C, xb, wr1b + (size_t)i * HID_C * IN_C,
        bl1 + i * HID_C, h1, nullptr, nullptr, i);
    // layer 2
    gather_k<HID_C><<<MP, 256, 0, stream>>>(h1, agg, rp, ci);
    gemm_dual_k<HID_C, HID_C, true, 0><<<dim3(MP / 128, HID_C / 128), 256, 0, stream>>>(
        agg, wl2b + (size_t)i * HID_C * HID_C, h1, wr2b + (size_t)i * HID_C * HID_C,
        bl2 + i * HID_C, h2, nullptr, nullptr, i);
    // layer 3 (combine into d_out fp32)
    gather_k<HID_C><<<MP, 256, 0, stream>>>(h2, agg, rp, ci);
    gemm_dual_k<OUT_C, HID_C, false, 1><<<dim3(MP / 128, OUT_C / 128), 256, 0, stream>>>(
        agg, wl3b + (size_t)i * OUT_C * HID_C, h2, wr3b + (size_t)i * OUT_C * HID_C,
        bl3 + i * OUT_C, nullptr, out, wsm, i);
  }

  l2norm_k<<<N_NODES, 128, 0, stream>>>(out);
}

// Round 2
// 3545.253 us; speedup vs baseline: 1.0941x; 1.0941x over previous
//
#include <hip/hip_runtime.h>
#include <hip/hip_bf16.h>
#include <stdint.h>

// ---------------- constants ----------------
#define N_NODES   20000
#define MP        20096          // padded to 157*128
#define N_TYPES   5
#define N_EDGES   64000
#define IN_C      2048
#define HID_C     1024
#define OUT_C     512

typedef __attribute__((ext_vector_type(8))) short short8;   // 8 bf16 (4 VGPR)
typedef __attribute__((ext_vector_type(4))) float f32x4;

// ---------------- helpers ----------------
__device__ __forceinline__ unsigned short f2b(float f) {
  union { float f; uint32_t u; } c; c.f = f;
  uint32_t u = c.u;
  u += 0x7FFFu + ((u >> 16) & 1u);          // RNE
  return (unsigned short)(u >> 16);
}
__device__ __forceinline__ float b2f(unsigned short h) {
  union { uint32_t u; float f; } c; c.u = ((uint32_t)h) << 16; return c.f;
}
__device__ __forceinline__ void gload_lds16(const void* g, void* l) {
  __builtin_amdgcn_global_load_lds((__attribute__((address_space(1))) void*)g,
                                   (__attribute__((address_space(3))) void*)l,
                                   16, 0, 0);
}

// ---------------- small prep kernels ----------------
__global__ __launch_bounds__(64) void softmax5_k(const float* __restrict__ attn, float* __restrict__ w) {
  if (threadIdx.x == 0) {
    float m = attn[0];
    for (int i = 1; i < N_TYPES; ++i) m = fmaxf(m, attn[i]);
    float e[N_TYPES], s = 0.f;
    for (int i = 0; i < N_TYPES; ++i) { e[i] = expf(attn[i] - m); s += e[i]; }
    for (int i = 0; i < N_TYPES; ++i) w[i] = e[i] / s;
  }
}

__global__ __launch_bounds__(256) void zero_int_k(int* __restrict__ p, int n) {
  int i = blockIdx.x * 256 + threadIdx.x;
  if (i < n) p[i] = 0;
}

__global__ __launch_bounds__(256) void hist_k(const int* __restrict__ edges, int* __restrict__ deg) {
  int t = blockIdx.x * 256 + threadIdx.x;
  if (t < N_TYPES * N_EDGES) {
    int ty = t / N_EDGES, e = t - ty * N_EDGES;
    int dst = edges[ty * 2 * N_EDGES + N_EDGES + e];
    atomicAdd(&deg[ty * N_NODES + dst], 1);
  }
}

__global__ __launch_bounds__(256) void scan_k(const int* __restrict__ deg, int* __restrict__ rowptr,
                                              int* __restrict__ cursor) {
  int ty = blockIdx.x;
  const int* d = deg + ty * N_NODES;
  int* rp = rowptr + ty * (N_NODES + 1);
  int* cu = cursor + ty * N_NODES;
  __shared__ int sh[256];
  __shared__ int s_carry;
  int tid = threadIdx.x;
  if (tid == 0) s_carry = 0;
  __syncthreads();
  for (int base = 0; base < N_NODES; base += 256) {
    int i = base + tid;
    int v = (i < N_NODES) ? d[i] : 0;
    sh[tid] = v; __syncthreads();
    for (int off = 1; off < 256; off <<= 1) {
      int t2 = (tid >= off) ? sh[tid - off] : 0;
      __syncthreads();
      sh[tid] += t2;
      __syncthreads();
    }
    int incl = sh[tid];
    int c = s_carry;
    if (i < N_NODES) { rp[i] = c + incl - v; cu[i] = c + incl - v; }
    __syncthreads();
    if (tid == 255) s_carry = c + incl;
    __syncthreads();
  }
  if (tid == 0) rp[N_NODES] = s_carry;
}

__global__ __launch_bounds__(256) void scatter_k(const int* __restrict__ edges, int* __restrict__ cursor,
                                                 int* __restrict__ colidx) {
  int t = blockIdx.x * 256 + threadIdx.x;
  if (t < N_TYPES * N_EDGES) {
    int ty = t / N_EDGES, e = t - ty * N_EDGES;
    int src = edges[ty * 2 * N_EDGES + e];
    int dst = edges[ty * 2 * N_EDGES + N_EDGES + e];
    int pos = atomicAdd(&cursor[ty * N_NODES + dst], 1);
    colidx[ty * N_EDGES + pos] = src;
  }
}

// x fp32 [20000,2048] -> bf16 [20096,2048], pad rows zero
__global__ __launch_bounds__(256) void cvt_x_k(const float* __restrict__ x, unsigned short* __restrict__ xb) {
  int i = blockIdx.x * 256 + threadIdx.x;     // [0, 20096*512)
  int row = i >> 9;
  int c4 = (i & 511) << 2;
  ushort4 o;
  if (row < N_NODES) {
    float4 v = *(const float4*)(x + (size_t)row * IN_C + c4);
    o.x = f2b(v.x); o.y = f2b(v.y); o.z = f2b(v.z); o.w = f2b(v.w);
  } else { o.x = 0; o.y = 0; o.z = 0; o.w = 0; }
  *(ushort4*)(xb + (size_t)row * IN_C + c4) = o;
}

__global__ __launch_bounds__(256) void cvt_w_k(const float* __restrict__ s, unsigned short* __restrict__ d, int n4) {
  int i = blockIdx.x * 256 + threadIdx.x;
  if (i < n4) {
    float4 v = ((const float4*)s)[i];
    ushort4 o; o.x = f2b(v.x); o.y = f2b(v.y); o.z = f2b(v.z); o.w = f2b(v.w);
    ((ushort4*)d)[i] = o;
  }
}

// ---------------- CSR mean-gather: Agg[n] = mean_{src in N(n)} H[src], bf16 in/out, fp32 accum ----------------
template<int C>
__global__ __launch_bounds__(256) void gather_k(const unsigned short* __restrict__ H,
                                                unsigned short* __restrict__ Agg,
                                                const int* __restrict__ rowptr,
                                                const int* __restrict__ colidx) {
  constexpr int V = C / 256;                 // 8 (C=2048) or 4 (C=1024)
  int node = blockIdx.x;
  int tid = threadIdx.x;
  float acc[V];
#pragma unroll
  for (int j = 0; j < V; ++j) acc[j] = 0.f;
  if (node < N_NODES) {
    int beg = rowptr[node], end = rowptr[node + 1];
    for (int e = beg; e < end; ++e) {
      int src = colidx[e];
      const unsigned short* p = H + (size_t)src * C + tid * V;
#pragma unroll
      for (int j = 0; j < V; j += 4) {
        ushort4 u = *(const ushort4*)(p + j);
        acc[j + 0] += b2f(u.x); acc[j + 1] += b2f(u.y);
        acc[j + 2] += b2f(u.z); acc[j + 3] += b2f(u.w);
      }
    }
    int dg = end - beg;
    float inv = dg > 0 ? 1.f / (float)dg : 0.f;
#pragma unroll
    for (int j = 0; j < V; ++j) acc[j] *= inv;
  }
  unsigned short* q = Agg + (size_t)node * C + tid * V;
#pragma unroll
  for (int j = 0; j < V; j += 4) {
    ushort4 o; o.x = f2b(acc[j]); o.y = f2b(acc[j + 1]); o.z = f2b(acc[j + 2]); o.w = f2b(acc[j + 3]);
    *(ushort4*)(q + j) = o;
  }
}

// ---------------- fused dual GEMM: C[M,N] = A1@W1^T + A2@W2^T + bias  (W row-major [N,K]) ----------------
// 128x128 tile, 4 waves (each 64x64 = 4x4 frags of 16x16), BK=32, global_load_lds staging.
// 1D grid, column-fastest decomposition + bijective XCD-chunked swizzle (m204):
// the NBLK col-blocks sharing an A row-tile become adjacent ids on the SAME XCD -> A hits L2.
// MODE 0: Hout(bf16, stride N, MP rows, pad rows zeroed), optional RELU.
// MODE 1: Cout fp32 [20000,N]: type 0 writes w*val, others += w*val.
template<int NSIZE, int KSIZE, bool RELU, int MODE>
__global__ __launch_bounds__(256) void gemm_dual_k(const unsigned short* __restrict__ A1,
                                                   const unsigned short* __restrict__ W1,
                                                   const unsigned short* __restrict__ A2,
                                                   const unsigned short* __restrict__ W2,
                                                   const float* __restrict__ bias,
                                                   unsigned short* __restrict__ Hout,
                                                   float* __restrict__ Cout,
                                                   const float* __restrict__ wsm, int itype) {
  __shared__ unsigned short As[128 * 32];
  __shared__ unsigned short Bs[128 * 32];
  const int tid = threadIdx.x;
  const int lane = tid & 63;
  const int wave = tid >> 6;
  const int wm = wave >> 1, wn = wave & 1;

  // --- XCD-chunked bijective swizzle (m204), column-fastest geometry ---
  constexpr int NBLK = NSIZE / 128;
  const int nwg = gridDim.x;
  const int flat = blockIdx.x;
  const int q = nwg >> 3, r = nwg & 7;
  const int xcd = flat & 7, idx = flat >> 3;
  const int wg = (xcd < r) ? (xcd * (q + 1) + idx) : (r * (q + 1) + (xcd - r) * q + idx);
  const int row0 = (wg / NBLK) * 128;
  const int col0 = (wg % NBLK) * 128;

  f32x4 acc[4][4];
#pragma unroll
  for (int m = 0; m < 4; ++m)
#pragma unroll
    for (int n = 0; n < 4; ++n) acc[m][n] = (f32x4)(0.f);

  const int lrow = lane >> 2;          // staging: row within 16-row group
  const int lkb = (lane & 3) * 8;      // staging: k element offset
  const int frow = lane & 15;          // fragment row/col
  const int fk = (lane >> 4) * 8;      // fragment k offset

  for (int seg = 0; seg < 2; ++seg) {
    const unsigned short* A = seg ? A2 : A1;
    const unsigned short* W = seg ? W2 : W1;
    for (int kb = 0; kb < KSIZE; kb += 32) {
      __syncthreads();
#pragma unroll
      for (int j = 0; j < 2; ++j) {
        int rs = (wave + 4 * j) * 16;
        gload_lds16(A + (size_t)(row0 + rs + lrow) * KSIZE + kb + lkb, &As[rs * 32]);
        gload_lds16(W + (size_t)(col0 + rs + lrow) * KSIZE + kb + lkb, &Bs[rs * 32]);
      }
      __syncthreads();
      short8 af[4], bfr[4];
#pragma unroll
      for (int m = 0; m < 4; ++m)
        af[m] = *(const short8*)&As[(wm * 64 + m * 16 + frow) * 32 + fk];
#pragma unroll
      for (int n = 0; n < 4; ++n)
        bfr[n] = *(const short8*)&Bs[(wn * 64 + n * 16 + frow) * 32 + fk];
#pragma unroll
      for (int m = 0; m < 4; ++m)
#pragma unroll
        for (int n = 0; n < 4; ++n)
          acc[m][n] = __builtin_amdgcn_mfma_f32_16x16x32_bf16(af[m], bfr[n], acc[m][n], 0, 0, 0);
    }
  }

  // epilogue: D layout col=lane&15, row=(lane>>4)*4+reg  [verified gfx950 mapping]
  const int erow = (lane >> 4) * 4;
  const int ecol = lane & 15;
  float wgt = (MODE == 1) ? wsm[itype] : 0.f;
#pragma unroll
  for (int m = 0; m < 4; ++m) {
#pragma unroll
    for (int n = 0; n < 4; ++n) {
      int gcol = col0 + wn * 64 + n * 16 + ecol;
      float bv = bias[gcol];
#pragma unroll
      for (int r = 0; r < 4; ++r) {
        int grow = row0 + wm * 64 + m * 16 + erow + r;
        float v = acc[m][n][r] + bv;
        if (RELU) v = fmaxf(v, 0.f);
        if (MODE == 0) {
          if (grow >= N_NODES) v = 0.f;   // keep pad rows zero
          Hout[(size_t)grow * NSIZE + gcol] = f2b(v);
        } else {
          if (grow < N_NODES) {
            size_t o = (size_t)grow * NSIZE + gcol;
            float ov = wgt * v;
            if (itype == 0) Cout[o] = ov; else Cout[o] += ov;
          }
        }
      }
    }
  }
}

// ---------------- final row L2 normalize (in place on d_out) ----------------
__global__ __launch_bounds__(128) void l2norm_k(float* __restrict__ out) {
  int row = blockIdx.x;
  int tid = threadIdx.x;                 // 128 threads * float4 = 512 cols
  float4 v = ((float4*)(out + (size_t)row * OUT_C))[tid];
  float ss = v.x * v.x + v.y * v.y + v.z * v.z + v.w * v.w;
  for (int off = 32; off > 0; off >>= 1) ss += __shfl_down(ss, off);
  __shared__ float s2[2];
  if ((tid & 63) == 0) s2[tid >> 6] = ss;
  __syncthreads();
  float tot = s2[0] + s2[1];
  float inv = 1.f / fmaxf(sqrtf(tot), 1e-12f);
  v.x *= inv; v.y *= inv; v.z *= inv; v.w *= inv;
  ((float4*)(out + (size_t)row * OUT_C))[tid] = v;
}

// ---------------- launch ----------------
extern "C" void kernel_launch(void* const* d_in, const int* in_sizes, int n_in,
                              void* d_out, int out_size, void* d_ws, size_t ws_size,
                              hipStream_t stream) {
  const float* x    = (const float*)d_in[0];
  const int*   edges = (const int*)d_in[1];
  const float* Wl1 = (const float*)d_in[2];
  const float* bl1 = (const float*)d_in[3];
  const float* Wr1 = (const float*)d_in[4];
  const float* Wl2 = (const float*)d_in[5];
  const float* bl2 = (const float*)d_in[6];
  const float* Wr2 = (const float*)d_in[7];
  const float* Wl3 = (const float*)d_in[8];
  const float* bl3 = (const float*)d_in[9];
  const float* Wr3 = (const float*)d_in[10];
  const float* attn = (const float*)d_in[11];
  float* out = (float*)d_out;

  char* ws = (char*)d_ws;
  size_t off = 0;
  auto alloc = [&](size_t bytes) -> char* {
    char* p = ws + off;
    off = (off + bytes + 255) & ~(size_t)255;
    return p;
  };
  float* wsm   = (float*)alloc(N_TYPES * 4);
  int* deg     = (int*)alloc((size_t)N_TYPES * N_NODES * 4);
  int* rowptr  = (int*)alloc((size_t)N_TYPES * (N_NODES + 1) * 4);
  int* cursor  = (int*)alloc((size_t)N_TYPES * N_NODES * 4);
  int* colidx  = (int*)alloc((size_t)N_TYPES * N_EDGES * 4);
  unsigned short* xb   = (unsigned short*)alloc((size_t)MP * IN_C * 2);
  unsigned short* agg  = (unsigned short*)alloc((size_t)MP * IN_C * 2);
  unsigned short* h1   = (unsigned short*)alloc((size_t)MP * HID_C * 2);
  unsigned short* h2   = (unsigned short*)alloc((size_t)MP * HID_C * 2);
  unsigned short* wl1b = (unsigned short*)alloc((size_t)N_TYPES * HID_C * IN_C * 2);
  unsigned short* wr1b = (unsigned short*)alloc((size_t)N_TYPES * HID_C * IN_C * 2);
  unsigned short* wl2b = (unsigned short*)alloc((size_t)N_TYPES * HID_C * HID_C * 2);
  unsigned short* wr2b = (unsigned short*)alloc((size_t)N_TYPES * HID_C * HID_C * 2);
  unsigned short* wl3b = (unsigned short*)alloc((size_t)N_TYPES * OUT_C * HID_C * 2);
  unsigned short* wr3b = (unsigned short*)alloc((size_t)N_TYPES * OUT_C * HID_C * 2);

  // prep
  softmax5_k<<<1, 64, 0, stream>>>(attn, wsm);
  zero_int_k<<<(N_TYPES * N_NODES + 255) / 256, 256, 0, stream>>>(deg, N_TYPES * N_NODES);
  hist_k<<<(N_TYPES * N_EDGES + 255) / 256, 256, 0, stream>>>(edges, deg);
  scan_k<<<N_TYPES, 256, 0, stream>>>(deg, rowptr, cursor);
  scatter_k<<<(N_TYPES * N_EDGES + 255) / 256, 256, 0, stream>>>(edges, cursor, colidx);

  cvt_x_k<<<(MP * IN_C / 4 + 255) / 256, 256, 0, stream>>>(x, xb);
  {
    int n4;
    n4 = N_TYPES * HID_C * IN_C / 4;
    cvt_w_k<<<(n4 + 255) / 256, 256, 0, stream>>>(Wl1, wl1b, n4);
    cvt_w_k<<<(n4 + 255) / 256, 256, 0, stream>>>(Wr1, wr1b, n4);
    n4 = N_TYPES * HID_C * HID_C / 4;
    cvt_w_k<<<(n4 + 255) / 256, 256, 0, stream>>>(Wl2, wl2b, n4);
    cvt_w_k<<<(n4 + 255) / 256, 256, 0, stream>>>(Wr2, wr2b, n4);
    n4 = N_TYPES * OUT_C * HID_C / 4;
    cvt_w_k<<<(n4 + 255) / 256, 256, 0, stream>>>(Wl3, wl3b, n4);
    cvt_w_k<<<(n4 + 255) / 256, 256, 0, stream>>>(Wr3, wr3b, n4);
  }

  for (int i = 0; i < N_TYPES; ++i) {
    const int* rp = rowptr + i * (N_NODES + 1);
    const int* ci = colidx + i * N_EDGES;
    // layer 1
    gather_k<IN_C><<<MP, 256, 0, stream>>>(xb, agg, rp, ci);
    gemm_dual_k<HID_C, IN_C, true, 0><<<(MP / 128) * (HID_C / 128), 256, 0, stream>>>(
        agg, wl1b + (size_t)i * HID_C * IN_C, xb, wr1b + (size_t)i * HID_C * IN_C,
        bl1 + i * HID_C, h1, nullptr, nullptr, i);
    // layer 2
    gather_k<HID_C><<<MP, 256, 0, stream>>>(h1, agg, rp, ci);
    gemm_dual_k<HID_C, HID_C, true, 0><<<(MP / 128) * (HID_C / 128), 256, 0, stream>>>(
        agg, wl2b + (size_t)i * HID_C * HID_C, h1, wr2b + (size_t)i * HID_C * HID_C,
        bl2 + i * HID_C, h2, nullptr, nullptr, i);
    // layer 3 (combine into d_out fp32)
    gather_k<HID_C><<<MP, 256, 0, stream>>>(h2, agg, rp, ci);
    gemm_dual_k<OUT_C, HID_C, false, 1><<<(MP / 128) * (OUT_C / 128), 256, 0, stream>>>(
        agg, wl3b + (size_t)i * OUT_C * HID_C, h2, wr3b + (size_t)i * OUT_C * HID_C,
        bl3 + i * OUT_C, nullptr, out, wsm, i);
  }

  l2norm_k<<<N_NODES, 128, 0, stream>>>(out);
}

// Round 3
// 3535.624 us; speedup vs baseline: 1.0971x; 1.0027x over previous
//
#include <hip/hip_runtime.h>
#include <hip/hip_bf16.h>
#include <stdint.h>

// ---------------- constants ----------------
#define N_NODES   20000
#define MPAD      20224          // padded to 79*256
#define N_TYPES   5
#define N_EDGES   64000
#define IN_C      2048
#define HID_C     1024
#define OUT_C     512

typedef __attribute__((ext_vector_type(8))) short short8;   // 8 bf16 (4 VGPR)
typedef __attribute__((ext_vector_type(4))) float f32x4;

// ---------------- helpers ----------------
__device__ __forceinline__ unsigned short f2b(float f) {
  union { float f; uint32_t u; } c; c.f = f;
  uint32_t u = c.u;
  u += 0x7FFFu + ((u >> 16) & 1u);          // RNE
  return (unsigned short)(u >> 16);
}
__device__ __forceinline__ float b2f(unsigned short h) {
  union { uint32_t u; float f; } c; c.u = ((uint32_t)h) << 16; return c.f;
}
__device__ __forceinline__ void gload_lds16(const void* g, void* l) {
  __builtin_amdgcn_global_load_lds((__attribute__((address_space(1))) void*)g,
                                   (__attribute__((address_space(3))) void*)l,
                                   16, 0, 0);
}

// ---------------- small prep kernels ----------------
__global__ __launch_bounds__(64) void softmax5_k(const float* __restrict__ attn, float* __restrict__ w) {
  if (threadIdx.x == 0) {
    float m = attn[0];
    for (int i = 1; i < N_TYPES; ++i) m = fmaxf(m, attn[i]);
    float e[N_TYPES], s = 0.f;
    for (int i = 0; i < N_TYPES; ++i) { e[i] = expf(attn[i] - m); s += e[i]; }
    for (int i = 0; i < N_TYPES; ++i) w[i] = e[i] / s;
  }
}

__global__ __launch_bounds__(256) void zero_int_k(int* __restrict__ p, int n) {
  int i = blockIdx.x * 256 + threadIdx.x;
  if (i < n) p[i] = 0;
}

__global__ __launch_bounds__(256) void hist_k(const int* __restrict__ edges, int* __restrict__ deg) {
  int t = blockIdx.x * 256 + threadIdx.x;
  if (t < N_TYPES * N_EDGES) {
    int ty = t / N_EDGES, e = t - ty * N_EDGES;
    int dst = edges[ty * 2 * N_EDGES + N_EDGES + e];
    atomicAdd(&deg[ty * N_NODES + dst], 1);
  }
}

__global__ __launch_bounds__(256) void scan_k(const int* __restrict__ deg, int* __restrict__ rowptr,
                                              int* __restrict__ cursor) {
  int ty = blockIdx.x;
  const int* d = deg + ty * N_NODES;
  int* rp = rowptr + ty * (N_NODES + 1);
  int* cu = cursor + ty * N_NODES;
  __shared__ int sh[256];
  __shared__ int s_carry;
  int tid = threadIdx.x;
  if (tid == 0) s_carry = 0;
  __syncthreads();
  for (int base = 0; base < N_NODES; base += 256) {
    int i = base + tid;
    int v = (i < N_NODES) ? d[i] : 0;
    sh[tid] = v; __syncthreads();
    for (int off = 1; off < 256; off <<= 1) {
      int t2 = (tid >= off) ? sh[tid - off] : 0;
      __syncthreads();
      sh[tid] += t2;
      __syncthreads();
    }
    int incl = sh[tid];
    int c = s_carry;
    if (i < N_NODES) { rp[i] = c + incl - v; cu[i] = c + incl - v; }
    __syncthreads();
    if (tid == 255) s_carry = c + incl;
    __syncthreads();
  }
  if (tid == 0) rp[N_NODES] = s_carry;
}

__global__ __launch_bounds__(256) void scatter_k(const int* __restrict__ edges, int* __restrict__ cursor,
                                                 int* __restrict__ colidx) {
  int t = blockIdx.x * 256 + threadIdx.x;
  if (t < N_TYPES * N_EDGES) {
    int ty = t / N_EDGES, e = t - ty * N_EDGES;
    int src = edges[ty * 2 * N_EDGES + e];
    int dst = edges[ty * 2 * N_EDGES + N_EDGES + e];
    int pos = atomicAdd(&cursor[ty * N_NODES + dst], 1);
    colidx[ty * N_EDGES + pos] = src;
  }
}

// x fp32 [20000,2048] -> bf16 [20224,2048], pad rows zero
__global__ __launch_bounds__(256) void cvt_x_k(const float* __restrict__ x, unsigned short* __restrict__ xb) {
  int i = blockIdx.x * 256 + threadIdx.x;     // [0, MPAD*512)
  int row = i >> 9;
  int c4 = (i & 511) << 2;
  if (row >= MPAD) return;
  ushort4 o;
  if (row < N_NODES) {
    float4 v = *(const float4*)(x + (size_t)row * IN_C + c4);
    o.x = f2b(v.x); o.y = f2b(v.y); o.z = f2b(v.z); o.w = f2b(v.w);
  } else { o.x = 0; o.y = 0; o.z = 0; o.w = 0; }
  *(ushort4*)(xb + (size_t)row * IN_C + c4) = o;
}

__global__ __launch_bounds__(256) void cvt_w_k(const float* __restrict__ s, unsigned short* __restrict__ d, int n4) {
  int i = blockIdx.x * 256 + threadIdx.x;
  if (i < n4) {
    float4 v = ((const float4*)s)[i];
    ushort4 o; o.x = f2b(v.x); o.y = f2b(v.y); o.z = f2b(v.z); o.w = f2b(v.w);
    ((ushort4*)d)[i] = o;
  }
}

// ---------------- CSR mean-gather: Agg[n] = mean_{src in N(n)} H[src], bf16 in/out, fp32 accum ----------------
template<int C>
__global__ __launch_bounds__(256) void gather_k(const unsigned short* __restrict__ H,
                                                unsigned short* __restrict__ Agg,
                                                const int* __restrict__ rowptr,
                                                const int* __restrict__ colidx) {
  constexpr int V = C / 256;                 // 8 (C=2048) or 4 (C=1024)
  int node = blockIdx.x;
  int tid = threadIdx.x;
  float acc[V];
#pragma unroll
  for (int j = 0; j < V; ++j) acc[j] = 0.f;
  if (node < N_NODES) {
    int beg = rowptr[node], end = rowptr[node + 1];
    for (int e = beg; e < end; ++e) {
      int src = colidx[e];
      const unsigned short* p = H + (size_t)src * C + tid * V;
#pragma unroll
      for (int j = 0; j < V; j += 4) {
        ushort4 u = *(const ushort4*)(p + j);
        acc[j + 0] += b2f(u.x); acc[j + 1] += b2f(u.y);
        acc[j + 2] += b2f(u.z); acc[j + 3] += b2f(u.w);
      }
    }
    int dg = end - beg;
    float inv = dg > 0 ? 1.f / (float)dg : 0.f;
#pragma unroll
    for (int j = 0; j < V; ++j) acc[j] *= inv;
  }
  unsigned short* q = Agg + (size_t)node * C + tid * V;
#pragma unroll
  for (int j = 0; j < V; j += 4) {
    ushort4 o; o.x = f2b(acc[j]); o.y = f2b(acc[j + 1]); o.z = f2b(acc[j + 2]); o.w = f2b(acc[j + 3]);
    *(ushort4*)(q + j) = o;
  }
}

// ---------------- fused dual GEMM, 256x256 tile, ring-4 counted-vmcnt pipeline ----------------
// C[M,N] = A1@W1^T + A2@W2^T + bias  (A [M,K] rm, W [N,K] rm, both bf16)
// 8 waves (2M x 4N), per-wave 128x64 output, BK=32, mfma_f32_16x16x32_bf16.
// LDS: 4 ring slots x (A 256x32 + B 256x32) bf16 = 128 KiB. Lookahead-2 staging:
//   iter t computes tile t from slot t&3 and stages tile t+2 into slot (t+2)&3
//   (= slot (t-2)&3, last read two iters ago -> safe after this iter's top barrier).
// Residency: in-order vmcnt(4) at iter top (only tile t+1's 4 loads may remain).
// T2 swizzle: lds_byte = (row*64 + k16*16) ^ ((row&3)<<4); staging keeps LDS dest
// linear (global_load_lds requirement) and XOR-permutes the global SOURCE per lane.
template<int NSIZE, int KSIZE, bool RELU, int MODE>
__global__ __launch_bounds__(512) void gemm_dual_k(const unsigned short* __restrict__ A1,
                                                   const unsigned short* __restrict__ W1,
                                                   const unsigned short* __restrict__ A2,
                                                   const unsigned short* __restrict__ W2,
                                                   const float* __restrict__ bias,
                                                   unsigned short* __restrict__ Hout,
                                                   float* __restrict__ Cout,
                                                   const float* __restrict__ wsm, int itype) {
  constexpr int KT = KSIZE / 32;
  constexpr int NT = 2 * KT;
  __shared__ unsigned short As[4][256 * 32];
  __shared__ unsigned short Bs[4][256 * 32];
  const int tid = threadIdx.x;
  const int lane = tid & 63;
  const int wave = tid >> 6;
  const int wm = wave >> 2, wn = wave & 3;     // 2 x 4 wave grid

  // --- XCD-chunked bijective swizzle (m204), column-fastest geometry ---
  constexpr int NBLK = NSIZE / 256;
  const int nwg = gridDim.x;
  const int flat = blockIdx.x;
  const int q8 = nwg >> 3, r8 = nwg & 7;
  const int xcd = flat & 7, idx = flat >> 3;
  const int wg = (xcd < r8) ? (xcd * (q8 + 1) + idx) : (r8 * (q8 + 1) + (xcd - r8) * q8 + idx);
  const int row0 = (wg / NBLK) * 256;
  const int col0 = (wg % NBLK) * 256;

  // staging lane decomposition: one gload_lds = wave writes 16 rows x 64B linear
  const int qq = lane >> 2;                          // row within the 16-row group
  const int csrc = (((lane & 3) ^ (qq & 3)) << 3);   // swizzle-compensated src elem offset

  auto stageA = [&](int t) {
    int s = t & 3; int seg = t >= KT; int kb = (t - (seg ? KT : 0)) * 32;
    const unsigned short* A = seg ? A2 : A1;
#pragma unroll
    for (int j = 0; j < 2; ++j) {
      int rs = (wave + 8 * j) * 16;
      gload_lds16(A + (size_t)(row0 + rs + qq) * KSIZE + kb + csrc, &As[s][rs * 32]);
    }
  };
  auto stageB = [&](int t) {
    int s = t & 3; int seg = t >= KT; int kb = (t - (seg ? KT : 0)) * 32;
    const unsigned short* W = seg ? W2 : W1;
#pragma unroll
    for (int j = 0; j < 2; ++j) {
      int rs = (wave + 8 * j) * 16;
      gload_lds16(W + (size_t)(col0 + rs + qq) * KSIZE + kb + csrc, &Bs[s][rs * 32]);
    }
  };

  f32x4 acc[8][4];
#pragma unroll
  for (int m = 0; m < 8; ++m)
#pragma unroll
    for (int n = 0; n < 4; ++n) acc[m][n] = (f32x4)(0.f);

  // prologue: tiles 0,1 fully staged (8 loads/wave outstanding)
  stageA(0); stageB(0);
  stageA(1); stageB(1);

  const int fr = lane & 15, k16 = lane >> 4;

  for (int t = 0; t < NT; ++t) {
    if (t < NT - 1) asm volatile("s_waitcnt vmcnt(4)" ::: "memory");
    else            asm volatile("s_waitcnt vmcnt(0)" ::: "memory");
    __builtin_amdgcn_s_barrier();
    __builtin_amdgcn_sched_barrier(0);
    const int s = t & 3;
    const char* pa = (const char*)As[s];
    const char* pb = (const char*)Bs[s];
    short8 bfr[4];
#pragma unroll
    for (int n = 0; n < 4; ++n) {
      int r = wn * 64 + n * 16 + fr;
      bfr[n] = *(const short8*)(pb + (((r << 6) + (k16 << 4)) ^ ((r & 3) << 4)));
    }
    short8 af[4];
#pragma unroll
    for (int m = 0; m < 4; ++m) {
      int r = wm * 128 + m * 16 + fr;
      af[m] = *(const short8*)(pa + (((r << 6) + (k16 << 4)) ^ ((r & 3) << 4)));
    }
    if (t + 2 < NT) stageA(t + 2);
    __builtin_amdgcn_s_setprio(1);
#pragma unroll
    for (int m = 0; m < 4; ++m)
#pragma unroll
      for (int n = 0; n < 4; ++n)
        acc[m][n] = __builtin_amdgcn_mfma_f32_16x16x32_bf16(af[m], bfr[n], acc[m][n], 0, 0, 0);
    __builtin_amdgcn_s_setprio(0);
    // phase 2: upper M half
#pragma unroll
    for (int m = 0; m < 4; ++m) {
      int r = wm * 128 + (m + 4) * 16 + fr;
      af[m] = *(const short8*)(pa + (((r << 6) + (k16 << 4)) ^ ((r & 3) << 4)));
    }
    if (t + 2 < NT) stageB(t + 2);
    __builtin_amdgcn_s_setprio(1);
#pragma unroll
    for (int m = 0; m < 4; ++m)
#pragma unroll
      for (int n = 0; n < 4; ++n)
        acc[m + 4][n] = __builtin_amdgcn_mfma_f32_16x16x32_bf16(af[m], bfr[n], acc[m + 4][n], 0, 0, 0);
    __builtin_amdgcn_s_setprio(0);
  }

  // epilogue: D layout col=lane&15, row=(lane>>4)*4+reg  [verified gfx950 mapping]
  const int erow = (lane >> 4) * 4;
  const int ecol = lane & 15;
  float wgt = (MODE == 1) ? wsm[itype] : 0.f;
#pragma unroll
  for (int m = 0; m < 8; ++m) {
#pragma unroll
    for (int n = 0; n < 4; ++n) {
      int gcol = col0 + wn * 64 + n * 16 + ecol;
      float bv = bias[gcol];
#pragma unroll
      for (int r = 0; r < 4; ++r) {
        int grow = row0 + wm * 128 + m * 16 + erow + r;
        float v = acc[m][n][r] + bv;
        if (RELU) v = fmaxf(v, 0.f);
        if (MODE == 0) {
          if (grow >= N_NODES) v = 0.f;   // keep pad rows zero
          Hout[(size_t)grow * NSIZE + gcol] = f2b(v);
        } else {
          if (grow < N_NODES) {
            size_t o = (size_t)grow * NSIZE + gcol;
            float ov = wgt * v;
            if (itype == 0) Cout[o] = ov; else Cout[o] += ov;
          }
        }
      }
    }
  }
}

// ---------------- final row L2 normalize (in place on d_out) ----------------
__global__ __launch_bounds__(128) void l2norm_k(float* __restrict__ out) {
  int row = blockIdx.x;
  int tid = threadIdx.x;                 // 128 threads * float4 = 512 cols
  float4 v = ((float4*)(out + (size_t)row * OUT_C))[tid];
  float ss = v.x * v.x + v.y * v.y + v.z * v.z + v.w * v.w;
  for (int off = 32; off > 0; off >>= 1) ss += __shfl_down(ss, off);
  __shared__ float s2[2];
  if ((tid & 63) == 0) s2[tid >> 6] = ss;
  __syncthreads();
  float tot = s2[0] + s2[1];
  float inv = 1.f / fmaxf(sqrtf(tot), 1e-12f);
  v.x *= inv; v.y *= inv; v.z *= inv; v.w *= inv;
  ((float4*)(out + (size_t)row * OUT_C))[tid] = v;
}

// ---------------- launch ----------------
extern "C" void kernel_launch(void* const* d_in, const int* in_sizes, int n_in,
                              void* d_out, int out_size, void* d_ws, size_t ws_size,
                              hipStream_t stream) {
  const float* x    = (const float*)d_in[0];
  const int*   edges = (const int*)d_in[1];
  const float* Wl1 = (const float*)d_in[2];
  const float* bl1 = (const float*)d_in[3];
  const float* Wr1 = (const float*)d_in[4];
  const float* Wl2 = (const float*)d_in[5];
  const float* bl2 = (const float*)d_in[6];
  const float* Wr2 = (const float*)d_in[7];
  const float* Wl3 = (const float*)d_in[8];
  const float* bl3 = (const float*)d_in[9];
  const float* Wr3 = (const float*)d_in[10];
  const float* attn = (const float*)d_in[11];
  float* out = (float*)d_out;

  char* ws = (char*)d_ws;
  size_t off = 0;
  auto alloc = [&](size_t bytes) -> char* {
    char* p = ws + off;
    off = (off + bytes + 255) & ~(size_t)255;
    return p;
  };
  float* wsm   = (float*)alloc(N_TYPES * 4);
  int* deg     = (int*)alloc((size_t)N_TYPES * N_NODES * 4);
  int* rowptr  = (int*)alloc((size_t)N_TYPES * (N_NODES + 1) * 4);
  int* cursor  = (int*)alloc((size_t)N_TYPES * N_NODES * 4);
  int* colidx  = (int*)alloc((size_t)N_TYPES * N_EDGES * 4);
  unsigned short* xb   = (unsigned short*)alloc((size_t)MPAD * IN_C * 2);
  unsigned short* agg  = (unsigned short*)alloc((size_t)MPAD * IN_C * 2);
  unsigned short* h1   = (unsigned short*)alloc((size_t)MPAD * HID_C * 2);
  unsigned short* h2   = (unsigned short*)alloc((size_t)MPAD * HID_C * 2);
  unsigned short* wl1b = (unsigned short*)alloc((size_t)N_TYPES * HID_C * IN_C * 2);
  unsigned short* wr1b = (unsigned short*)alloc((size_t)N_TYPES * HID_C * IN_C * 2);
  unsigned short* wl2b = (unsigned short*)alloc((size_t)N_TYPES * HID_C * HID_C * 2);
  unsigned short* wr2b = (unsigned short*)alloc((size_t)N_TYPES * HID_C * HID_C * 2);
  unsigned short* wl3b = (unsigned short*)alloc((size_t)N_TYPES * OUT_C * HID_C * 2);
  unsigned short* wr3b = (unsigned short*)alloc((size_t)N_TYPES * OUT_C * HID_C * 2);

  // prep
  softmax5_k<<<1, 64, 0, stream>>>(attn, wsm);
  zero_int_k<<<(N_TYPES * N_NODES + 255) / 256, 256, 0, stream>>>(deg, N_TYPES * N_NODES);
  hist_k<<<(N_TYPES * N_EDGES + 255) / 256, 256, 0, stream>>>(edges, deg);
  scan_k<<<N_TYPES, 256, 0, stream>>>(deg, rowptr, cursor);
  scatter_k<<<(N_TYPES * N_EDGES + 255) / 256, 256, 0, stream>>>(edges, cursor, colidx);

  cvt_x_k<<<((size_t)MPAD * IN_C / 4 + 255) / 256, 256, 0, stream>>>(x, xb);
  {
    int n4;
    n4 = N_TYPES * HID_C * IN_C / 4;
    cvt_w_k<<<(n4 + 255) / 256, 256, 0, stream>>>(Wl1, wl1b, n4);
    cvt_w_k<<<(n4 + 255) / 256, 256, 0, stream>>>(Wr1, wr1b, n4);
    n4 = N_TYPES * HID_C * HID_C / 4;
    cvt_w_k<<<(n4 + 255) / 256, 256, 0, stream>>>(Wl2, wl2b, n4);
    cvt_w_k<<<(n4 + 255) / 256, 256, 0, stream>>>(Wr2, wr2b, n4);
    n4 = N_TYPES * OUT_C * HID_C / 4;
    cvt_w_k<<<(n4 + 255) / 256, 256, 0, stream>>>(Wl3, wl3b, n4);
    cvt_w_k<<<(n4 + 255) / 256, 256, 0, stream>>>(Wr3, wr3b, n4);
  }

  for (int i = 0; i < N_TYPES; ++i) {
    const int* rp = rowptr + i * (N_NODES + 1);
    const int* ci = colidx + i * N_EDGES;
    // layer 1
    gather_k<IN_C><<<MPAD, 256, 0, stream>>>(xb, agg, rp, ci);
    gemm_dual_k<HID_C, IN_C, true, 0><<<(MPAD / 256) * (HID_C / 256), 512, 0, stream>>>(
        agg, wl1b + (size_t)i * HID_C * IN_C, xb, wr1b + (size_t)i * HID_C * IN_C,
        bl1 + i * HID_C, h1, nullptr, nullptr, i);
    // layer 2
    gather_k<HID_C><<<MPAD, 256, 0, stream>>>(h1, agg, rp, ci);
    gemm_dual_k<HID_C, HID_C, true, 0><<<(MPAD / 256) * (HID_C / 256), 512, 0, stream>>>(
        agg, wl2b + (size_t)i * HID_C * HID_C, h1, wr2b + (size_t)i * HID_C * HID_C,
        bl2 + i * HID_C, h2, nullptr, nullptr, i);
    // layer 3 (combine into d_out fp32)
    gather_k<HID_C><<<MPAD, 256, 0, stream>>>(h2, agg, rp, ci);
    gemm_dual_k<OUT_C, HID_C, false, 1><<<(MPAD / 256) * (OUT_C / 256), 512, 0, stream>>>(
        agg, wl3b + (size_t)i * OUT_C * HID_C, h2, wr3b + (size_t)i * OUT_C * HID_C,
        bl3 + i * OUT_C, nullptr, out, wsm, i);
  }

  l2norm_k<<<N_NODES, 128, 0, stream>>>(out);
}

// Round 4
// 3340.558 us; speedup vs baseline: 1.1611x; 1.0584x over previous
//
#include <hip/hip_runtime.h>
#include <hip/hip_bf16.h>
#include <stdint.h>

// ---------------- constants ----------------
#define N_NODES   20000
#define MPAD      20224          // padded to 79*256
#define N_TYPES   5
#define N_EDGES   64000
#define IN_C      2048
#define HID_C     1024
#define OUT_C     512

typedef __attribute__((ext_vector_type(8))) short short8;   // 8 bf16 (4 VGPR)
typedef __attribute__((ext_vector_type(4))) float f32x4;

// ---------------- helpers ----------------
__device__ __forceinline__ unsigned short f2b(float f) {
  union { float f; uint32_t u; } c; c.f = f;
  uint32_t u = c.u;
  u += 0x7FFFu + ((u >> 16) & 1u);          // RNE
  return (unsigned short)(u >> 16);
}
__device__ __forceinline__ float b2f(unsigned short h) {
  union { uint32_t u; float f; } c; c.u = ((uint32_t)h) << 16; return c.f;
}
__device__ __forceinline__ void gload_lds16(const void* g, void* l) {
  __builtin_amdgcn_global_load_lds((__attribute__((address_space(1))) void*)g,
                                   (__attribute__((address_space(3))) void*)l,
                                   16, 0, 0);
}

// ---------------- small prep kernels ----------------
__global__ __launch_bounds__(64) void softmax5_k(const float* __restrict__ attn, float* __restrict__ w) {
  if (threadIdx.x == 0) {
    float m = attn[0];
    for (int i = 1; i < N_TYPES; ++i) m = fmaxf(m, attn[i]);
    float e[N_TYPES], s = 0.f;
    for (int i = 0; i < N_TYPES; ++i) { e[i] = expf(attn[i] - m); s += e[i]; }
    for (int i = 0; i < N_TYPES; ++i) w[i] = e[i] / s;
  }
}

__global__ __launch_bounds__(256) void zero_int_k(int* __restrict__ p, int n) {
  int i = blockIdx.x * 256 + threadIdx.x;
  if (i < n) p[i] = 0;
}

__global__ __launch_bounds__(256) void hist_k(const int* __restrict__ edges, int* __restrict__ deg) {
  int t = blockIdx.x * 256 + threadIdx.x;
  if (t < N_TYPES * N_EDGES) {
    int ty = t / N_EDGES, e = t - ty * N_EDGES;
    int dst = edges[ty * 2 * N_EDGES + N_EDGES + e];
    atomicAdd(&deg[ty * N_NODES + dst], 1);
  }
}

__global__ __launch_bounds__(256) void scan_k(const int* __restrict__ deg, int* __restrict__ rowptr,
                                              int* __restrict__ cursor) {
  int ty = blockIdx.x;
  const int* d = deg + ty * N_NODES;
  int* rp = rowptr + ty * (N_NODES + 1);
  int* cu = cursor + ty * N_NODES;
  __shared__ int sh[256];
  __shared__ int s_carry;
  int tid = threadIdx.x;
  if (tid == 0) s_carry = 0;
  __syncthreads();
  for (int base = 0; base < N_NODES; base += 256) {
    int i = base + tid;
    int v = (i < N_NODES) ? d[i] : 0;
    sh[tid] = v; __syncthreads();
    for (int off = 1; off < 256; off <<= 1) {
      int t2 = (tid >= off) ? sh[tid - off] : 0;
      __syncthreads();
      sh[tid] += t2;
      __syncthreads();
    }
    int incl = sh[tid];
    int c = s_carry;
    if (i < N_NODES) { rp[i] = c + incl - v; cu[i] = c + incl - v; }
    __syncthreads();
    if (tid == 255) s_carry = c + incl;
    __syncthreads();
  }
  if (tid == 0) rp[N_NODES] = s_carry;
}

__global__ __launch_bounds__(256) void scatter_k(const int* __restrict__ edges, int* __restrict__ cursor,
                                                 int* __restrict__ colidx) {
  int t = blockIdx.x * 256 + threadIdx.x;
  if (t < N_TYPES * N_EDGES) {
    int ty = t / N_EDGES, e = t - ty * N_EDGES;
    int src = edges[ty * 2 * N_EDGES + e];
    int dst = edges[ty * 2 * N_EDGES + N_EDGES + e];
    int pos = atomicAdd(&cursor[ty * N_NODES + dst], 1);
    colidx[ty * N_EDGES + pos] = src;
  }
}

// x fp32 [20000,2048] -> bf16 [20224,2048], pad rows zero
__global__ __launch_bounds__(256) void cvt_x_k(const float* __restrict__ x, unsigned short* __restrict__ xb) {
  int i = blockIdx.x * 256 + threadIdx.x;
  int row = i >> 9;
  int c4 = (i & 511) << 2;
  if (row >= MPAD) return;
  ushort4 o;
  if (row < N_NODES) {
    float4 v = *(const float4*)(x + (size_t)row * IN_C + c4);
    o.x = f2b(v.x); o.y = f2b(v.y); o.z = f2b(v.z); o.w = f2b(v.w);
  } else { o.x = 0; o.y = 0; o.z = 0; o.w = 0; }
  *(ushort4*)(xb + (size_t)row * IN_C + c4) = o;
}

__global__ __launch_bounds__(256) void cvt_w_k(const float* __restrict__ s, unsigned short* __restrict__ d, int n4) {
  int i = blockIdx.x * 256 + threadIdx.x;
  if (i < n4) {
    float4 v = ((const float4*)s)[i];
    ushort4 o; o.x = f2b(v.x); o.y = f2b(v.y); o.z = f2b(v.z); o.w = f2b(v.w);
    ((ushort4*)d)[i] = o;
  }
}

// ---------------- CSR mean-gather (type-batched): grid = nt*MPAD blocks ----------------
template<int C>
__global__ __launch_bounds__(256) void gather_k(const unsigned short* __restrict__ H, size_t hTS,
                                                unsigned short* __restrict__ Agg, size_t aggTS,
                                                const int* __restrict__ rowptr,
                                                const int* __restrict__ colidx, int it0) {
  constexpr int V = C / 256;
  int it = it0 + blockIdx.x / MPAD;
  int node = blockIdx.x % MPAD;
  const unsigned short* Hp = H + (size_t)it * hTS;
  unsigned short* Ap = Agg + (size_t)(it - it0) * aggTS;   // agg slab index local to dispatch
  const int* rp = rowptr + (size_t)it * (N_NODES + 1);
  const int* ci = colidx + (size_t)it * N_EDGES;
  int tid = threadIdx.x;
  float acc[V];
#pragma unroll
  for (int j = 0; j < V; ++j) acc[j] = 0.f;
  if (node < N_NODES) {
    int beg = rp[node], end = rp[node + 1];
    for (int e = beg; e < end; ++e) {
      int src = ci[e];
      const unsigned short* p = Hp + (size_t)src * C + tid * V;
#pragma unroll
      for (int j = 0; j < V; j += 4) {
        ushort4 u = *(const ushort4*)(p + j);
        acc[j + 0] += b2f(u.x); acc[j + 1] += b2f(u.y);
        acc[j + 2] += b2f(u.z); acc[j + 3] += b2f(u.w);
      }
    }
    int dg = end - beg;
    float inv = dg > 0 ? 1.f / (float)dg : 0.f;
#pragma unroll
    for (int j = 0; j < V; ++j) acc[j] *= inv;
  }
  unsigned short* q = Ap + (size_t)node * C + tid * V;
#pragma unroll
  for (int j = 0; j < V; j += 4) {
    ushort4 o; o.x = f2b(acc[j]); o.y = f2b(acc[j + 1]); o.z = f2b(acc[j + 2]); o.w = f2b(acc[j + 3]);
    *(ushort4*)(q + j) = o;
  }
}

// ---------------- fused dual GEMM, type-batched, 256x256 tile, ring-4 + phase-split ----------------
// C[M,N] = A1@W1^T + A2@W2^T + bias. 8 waves (2Mx4N), per-wave 128x64, BK=32.
// LDS: 4 ring slots x (A[256x32] + B[256x32]) = 128 KiB; lookahead-3 staging, vmcnt(8) steady.
// LDS unit layout: [128 LDS-rows][128 B] (two K32 tile-rows per LDS-row);
// swizzle: phys = logical ^ ((ldsrow&7)<<4)  -> wave b128 reads hit 2 lanes/16B-slot (free).
// Staging keeps LDS dest linear (global_load_lds requirement); the global SOURCE address is
// permuted per lane with the inverse mapping (verified bijective + element-traced).
template<int NSIZE, int KSIZE, bool RELU, int MODE>
__global__ __launch_bounds__(512, 2) void gemm_dual_k(
    const unsigned short* __restrict__ A1, size_t a1S,
    const unsigned short* __restrict__ W1,
    const unsigned short* __restrict__ A2, size_t a2S,
    const unsigned short* __restrict__ W2,
    const float* __restrict__ bias,
    unsigned short* __restrict__ Hout, float* __restrict__ Cout,
    const float* __restrict__ wsm, int it0, int accmode) {
  constexpr int KT = KSIZE / 32;
  constexpr int NT = 2 * KT;
  constexpr int MT = MPAD / 256;
  constexpr int NB = NSIZE / 256;
  __shared__ unsigned short As[4][8192];    // 4 x 16 KiB
  __shared__ unsigned short Bs[4][8192];
  const int tid = threadIdx.x;
  const int lane = tid & 63;
  const int wave = tid >> 6;
  const int wm = wave >> 2, wn = wave & 3;  // 2 x 4 wave grid

  // --- XCD-chunked bijective swizzle over the whole (type x tile) grid ---
  const int nwg = gridDim.x;
  const int flat = blockIdx.x;
  const int q8 = nwg >> 3, r8 = nwg & 7;
  const int xcd = flat & 7, idx = flat >> 3;
  const int wg = (xcd < r8) ? (xcd * (q8 + 1) + idx) : (r8 * (q8 + 1) + (xcd - r8) * q8 + idx);
  const int itl = wg / (MT * NB);           // type index local to dispatch
  const int it = it0 + itl;                 // global type index (weights/bias/wsm)
  const int rem = wg % (MT * NB);
  const int row0 = (rem / NB) * 256;
  const int col0 = (rem % NB) * 256;

  const unsigned short* A1p = A1 + (size_t)itl * a1S;
  const unsigned short* A2p = A2 + (size_t)itl * a2S;
  const unsigned short* W1p = W1 + (size_t)it * NSIZE * KSIZE;
  const unsigned short* W2p = W2 + (size_t)it * NSIZE * KSIZE;

  // staging lane constants (inverse of read swizzle)
  const int sR = lane >> 3;                    // LDS-row within 8-LDS-row region
  const int su = (lane & 7) ^ (sR & 7);        // swizzled 16B-slot within 128B LDS-row
  const int srow = 2 * sR + (su >> 2);         // tile-row within 16-row region
  const int selem = (su & 3) * 8;              // k element offset (8 bf16 = 16 B)

  // fragment read byte offsets (per-lane constants)
  const int fr = lane & 15, k16 = lane >> 4;
  int aoff[8], boff[4];
#pragma unroll
  for (int m = 0; m < 8; ++m) {
    int r = wm * 128 + m * 16 + fr;
    aoff[m] = (((r >> 1) << 7) + ((r & 1) << 6) + (k16 << 4)) ^ (((r >> 1) & 7) << 4);
  }
#pragma unroll
  for (int n = 0; n < 4; ++n) {
    int r = wn * 64 + n * 16 + fr;
    boff[n] = (((r >> 1) << 7) + ((r & 1) << 6) + (k16 << 4)) ^ (((r >> 1) & 7) << 4);
  }

  auto stageA = [&](int t) {
    int s = t & 3; int seg = t >= KT; int kb = (t - (seg ? KT : 0)) * 32;
    const unsigned short* A = seg ? A2p : A1p;
#pragma unroll
    for (int j = 0; j < 2; ++j) {
      int reg = wave + 8 * j;                  // 16 tile-rows (1024 B) per region
      gload_lds16(A + (size_t)(row0 + reg * 16 + srow) * KSIZE + kb + selem, &As[s][reg * 512]);
    }
  };
  auto stageB = [&](int t) {
    int s = t & 3; int seg = t >= KT; int kb = (t - (seg ? KT : 0)) * 32;
    const unsigned short* W = seg ? W2p : W1p;
#pragma unroll
    for (int j = 0; j < 2; ++j) {
      int reg = wave + 8 * j;
      gload_lds16(W + (size_t)(col0 + reg * 16 + srow) * KSIZE + kb + selem, &Bs[s][reg * 512]);
    }
  };

  f32x4 acc[8][4];
#pragma unroll
  for (int m = 0; m < 8; ++m)
#pragma unroll
    for (int n = 0; n < 4; ++n) acc[m][n] = (f32x4)(0.f);

  // prologue: tiles 0,1,2 in flight (12 loads/wave)
  stageA(0); stageB(0);
  stageA(1); stageB(1);
  stageA(2); stageB(2);

  for (int t = 0; t < NT; ++t) {
    if (t < NT - 2)       asm volatile("s_waitcnt vmcnt(8)" ::: "memory");
    else if (t == NT - 2) asm volatile("s_waitcnt vmcnt(4)" ::: "memory");
    else                  asm volatile("s_waitcnt vmcnt(0)" ::: "memory");
    __builtin_amdgcn_s_barrier();
    __builtin_amdgcn_sched_barrier(0);
    const int slot = t & 3;
    const char* pa = (const char*)As[slot];
    const char* pb = (const char*)Bs[slot];
    // phase 0: read B (kept in regs for both phases) + A lower; stage A(t+3); MFMA lower
    short8 bf[4];
#pragma unroll
    for (int n = 0; n < 4; ++n) bf[n] = *(const short8*)(pb + boff[n]);
    short8 af[4];
#pragma unroll
    for (int m = 0; m < 4; ++m) af[m] = *(const short8*)(pa + aoff[m]);
    if (t + 3 < NT) stageA(t + 3);
    __builtin_amdgcn_s_setprio(1);
#pragma unroll
    for (int m = 0; m < 4; ++m)
#pragma unroll
      for (int n = 0; n < 4; ++n)
        acc[m][n] = __builtin_amdgcn_mfma_f32_16x16x32_bf16(af[m], bf[n], acc[m][n], 0, 0, 0);
    __builtin_amdgcn_s_setprio(0);
    __builtin_amdgcn_s_barrier();
    __builtin_amdgcn_sched_barrier(0);
    // phase 1: read A upper; stage B(t+3); MFMA upper
#pragma unroll
    for (int m = 0; m < 4; ++m) af[m] = *(const short8*)(pa + aoff[m + 4]);
    if (t + 3 < NT) stageB(t + 3);
    __builtin_amdgcn_s_setprio(1);
#pragma unroll
    for (int m = 0; m < 4; ++m)
#pragma unroll
      for (int n = 0; n < 4; ++n)
        acc[m + 4][n] = __builtin_amdgcn_mfma_f32_16x16x32_bf16(af[m], bf[n], acc[m + 4][n], 0, 0, 0);
    __builtin_amdgcn_s_setprio(0);
  }

  // epilogue: D layout col=lane&15, row=(lane>>4)*4+reg  [verified gfx950 mapping]
  const int erow = (lane >> 4) * 4;
  const int ecol = lane & 15;
  float wgt = (MODE == 1) ? wsm[it] : 0.f;
#pragma unroll
  for (int m = 0; m < 8; ++m) {
#pragma unroll
    for (int n = 0; n < 4; ++n) {
      int gcol = col0 + wn * 64 + n * 16 + ecol;
      float bv = bias[(size_t)it * NSIZE + gcol];
#pragma unroll
      for (int r = 0; r < 4; ++r) {
        int grow = row0 + wm * 128 + m * 16 + erow + r;
        float v = acc[m][n][r] + bv;
        if (RELU) v = fmaxf(v, 0.f);
        if (MODE == 0) {
          if (grow >= N_NODES) v = 0.f;
          Hout[(size_t)itl * MPAD * NSIZE + (size_t)grow * NSIZE + gcol] = f2b(v);
        } else {
          if (grow < N_NODES) {
            size_t o = (size_t)itl * ((accmode < 0) ? (size_t)MPAD * NSIZE : 0)
                     + (size_t)grow * NSIZE + gcol;
            float ov = wgt * v;
            if (accmode == 1) Cout[o] += ov; else Cout[o] = ov;
          }
        }
      }
    }
  }
}

// ---------------- combine (sum weighted parts) + row L2 normalize -> d_out ----------------
__global__ __launch_bounds__(128) void combine_norm_k(const float* __restrict__ parts, size_t pS,
                                                      int nt, float* __restrict__ out) {
  int row = blockIdx.x;
  int tid = threadIdx.x;                 // 128 threads * float4 = 512 cols
  float4 v = {0.f, 0.f, 0.f, 0.f};
  for (int i = 0; i < nt; ++i) {
    float4 p = ((const float4*)(parts + (size_t)i * pS + (size_t)row * OUT_C))[tid];
    v.x += p.x; v.y += p.y; v.z += p.z; v.w += p.w;
  }
  float ss = v.x * v.x + v.y * v.y + v.z * v.z + v.w * v.w;
  for (int off = 32; off > 0; off >>= 1) ss += __shfl_down(ss, off);
  __shared__ float s2[2];
  if ((tid & 63) == 0) s2[tid >> 6] = ss;
  __syncthreads();
  float tot = s2[0] + s2[1];
  float inv = 1.f / fmaxf(sqrtf(tot), 1e-12f);
  v.x *= inv; v.y *= inv; v.z *= inv; v.w *= inv;
  ((float4*)(out + (size_t)row * OUT_C))[tid] = v;
}

// ---------------- launch ----------------
extern "C" void kernel_launch(void* const* d_in, const int* in_sizes, int n_in,
                              void* d_out, int out_size, void* d_ws, size_t ws_size,
                              hipStream_t stream) {
  const float* x    = (const float*)d_in[0];
  const int*   edges = (const int*)d_in[1];
  const float* Wl1 = (const float*)d_in[2];
  const float* bl1 = (const float*)d_in[3];
  const float* Wr1 = (const float*)d_in[4];
  const float* Wl2 = (const float*)d_in[5];
  const float* bl2 = (const float*)d_in[6];
  const float* Wr2 = (const float*)d_in[7];
  const float* Wl3 = (const float*)d_in[8];
  const float* bl3 = (const float*)d_in[9];
  const float* Wr3 = (const float*)d_in[10];
  const float* attn = (const float*)d_in[11];
  float* out = (float*)d_out;

  char* ws = (char*)d_ws;
  size_t off = 0;
  auto alloc = [&](size_t bytes) -> char* {
    char* p = ws + off;
    off = (off + bytes + 255) & ~(size_t)255;
    return p;
  };
  float* wsm   = (float*)alloc(N_TYPES * 4);
  int* deg     = (int*)alloc((size_t)N_TYPES * N_NODES * 4);
  int* rowptr  = (int*)alloc((size_t)N_TYPES * (N_NODES + 1) * 4);
  int* cursor  = (int*)alloc((size_t)N_TYPES * N_NODES * 4);
  int* colidx  = (int*)alloc((size_t)N_TYPES * N_EDGES * 4);
  unsigned short* xb   = (unsigned short*)alloc((size_t)MPAD * IN_C * 2);
  unsigned short* wl1b = (unsigned short*)alloc((size_t)N_TYPES * HID_C * IN_C * 2);
  unsigned short* wr1b = (unsigned short*)alloc((size_t)N_TYPES * HID_C * IN_C * 2);
  unsigned short* wl2b = (unsigned short*)alloc((size_t)N_TYPES * HID_C * HID_C * 2);
  unsigned short* wr2b = (unsigned short*)alloc((size_t)N_TYPES * HID_C * HID_C * 2);
  unsigned short* wl3b = (unsigned short*)alloc((size_t)N_TYPES * OUT_C * HID_C * 2);
  unsigned short* wr3b = (unsigned short*)alloc((size_t)N_TYPES * OUT_C * HID_C * 2);

  size_t off_common = off;
  unsigned short* aggBig = (unsigned short*)alloc((size_t)N_TYPES * MPAD * IN_C * 2);   // ~414 MB
  unsigned short* h1b    = (unsigned short*)alloc((size_t)N_TYPES * MPAD * HID_C * 2);  // ~207 MB
  size_t need_batched = off;
  bool batched = (ws_size >= need_batched);

  // prep
  softmax5_k<<<1, 64, 0, stream>>>(attn, wsm);
  zero_int_k<<<(N_TYPES * N_NODES + 255) / 256, 256, 0, stream>>>(deg, N_TYPES * N_NODES);
  hist_k<<<(N_TYPES * N_EDGES + 255) / 256, 256, 0, stream>>>(edges, deg);
  scan_k<<<N_TYPES, 256, 0, stream>>>(deg, rowptr, cursor);
  scatter_k<<<(N_TYPES * N_EDGES + 255) / 256, 256, 0, stream>>>(edges, cursor, colidx);

  cvt_x_k<<<((size_t)MPAD * IN_C / 4 + 255) / 256, 256, 0, stream>>>(x, xb);
  {
    int n4;
    n4 = N_TYPES * HID_C * IN_C / 4;
    cvt_w_k<<<(n4 + 255) / 256, 256, 0, stream>>>(Wl1, wl1b, n4);
    cvt_w_k<<<(n4 + 255) / 256, 256, 0, stream>>>(Wr1, wr1b, n4);
    n4 = N_TYPES * HID_C * HID_C / 4;
    cvt_w_k<<<(n4 + 255) / 256, 256, 0, stream>>>(Wl2, wl2b, n4);
    cvt_w_k<<<(n4 + 255) / 256, 256, 0, stream>>>(Wr2, wr2b, n4);
    n4 = N_TYPES * OUT_C * HID_C / 4;
    cvt_w_k<<<(n4 + 255) / 256, 256, 0, stream>>>(Wl3, wl3b, n4);
    cvt_w_k<<<(n4 + 255) / 256, 256, 0, stream>>>(Wr3, wr3b, n4);
  }

  const int MT = MPAD / 256;

  if (batched) {
    unsigned short* aggS = aggBig;                                        // 5 x [MPAD x 1024]
    unsigned short* h2b  = aggBig + (size_t)N_TYPES * MPAD * HID_C;       // 5 x [MPAD x 1024]
    float* parts         = (float*)h1b;                                   // 5 x [MPAD x 512] fp32

    // layer 1 (all 5 types in one dispatch per kernel)
    gather_k<IN_C><<<N_TYPES * MPAD, 256, 0, stream>>>(xb, 0, aggBig, (size_t)MPAD * IN_C,
                                                       rowptr, colidx, 0);
    gemm_dual_k<HID_C, IN_C, true, 0><<<N_TYPES * MT * (HID_C / 256), 512, 0, stream>>>(
        aggBig, (size_t)MPAD * IN_C, wl1b, xb, 0, wr1b, bl1, h1b, nullptr, wsm, 0, -1);
    // layer 2
    gather_k<HID_C><<<N_TYPES * MPAD, 256, 0, stream>>>(h1b, (size_t)MPAD * HID_C, aggS,
                                                        (size_t)MPAD * HID_C, rowptr, colidx, 0);
    gemm_dual_k<HID_C, HID_C, true, 0><<<N_TYPES * MT * (HID_C / 256), 512, 0, stream>>>(
        aggS, (size_t)MPAD * HID_C, wl2b, h1b, (size_t)MPAD * HID_C, wr2b, bl2, h2b, nullptr, wsm, 0, -1);
    // layer 3 -> weighted parts (agg3 reuses aggS region; h1 region reused for parts)
    gather_k<HID_C><<<N_TYPES * MPAD, 256, 0, stream>>>(h2b, (size_t)MPAD * HID_C, aggS,
                                                        (size_t)MPAD * HID_C, rowptr, colidx, 0);
    gemm_dual_k<OUT_C, HID_C, false, 1><<<N_TYPES * MT * (OUT_C / 256), 512, 0, stream>>>(
        aggS, (size_t)MPAD * HID_C, wl3b, h2b, (size_t)MPAD * HID_C, wr3b, bl3, nullptr, parts, wsm, 0, -1);

    combine_norm_k<<<N_NODES, 128, 0, stream>>>(parts, (size_t)MPAD * OUT_C, N_TYPES, out);
  } else {
    // fallback: per-type serial, small footprint (kernels identical, nt=1 per dispatch)
    off = off_common;
    unsigned short* agg = (unsigned short*)alloc((size_t)MPAD * IN_C * 2);
    unsigned short* h1  = (unsigned short*)alloc((size_t)MPAD * HID_C * 2);
    unsigned short* h2  = (unsigned short*)alloc((size_t)MPAD * HID_C * 2);
    float* part         = (float*)alloc((size_t)MPAD * OUT_C * 4);

    for (int i = 0; i < N_TYPES; ++i) {
      gather_k<IN_C><<<MPAD, 256, 0, stream>>>(xb, 0, agg, 0, rowptr, colidx, i);
      gemm_dual_k<HID_C, IN_C, true, 0><<<MT * (HID_C / 256), 512, 0, stream>>>(
          agg, 0, wl1b, xb, 0, wr1b, bl1, h1, nullptr, wsm, i, -1);
      gather_k<HID_C><<<MPAD, 256, 0, stream>>>(h1, 0, agg, 0, rowptr, colidx, i);
      gemm_dual_k<HID_C, HID_C, true, 0><<<MT * (HID_C / 256), 512, 0, stream>>>(
          agg, 0, wl2b, h1, 0, wr2b, bl2, h2, nullptr, wsm, i, -1);
      gather_k<HID_C><<<MPAD, 256, 0, stream>>>(h2, 0, agg, 0, rowptr, colidx, i);
      gemm_dual_k<OUT_C, HID_C, false, 1><<<MT * (OUT_C / 256), 512, 0, stream>>>(
          agg, 0, wl3b, h2, 0, wr3b, bl3, nullptr, part, wsm, i, (i == 0) ? 0 : 1);
    }
    combine_norm_k<<<N_NODES, 128, 0, stream>>>(part, 0, 1, out);
  }
}

// Round 5
// 2305.650 us; speedup vs baseline: 1.6823x; 1.4489x over previous
//
#include <hip/hip_runtime.h>
#include <hip/hip_bf16.h>
#include <stdint.h>

// ---------------- constants ----------------
#define N_NODES   20000
#define MPAD      20224          // padded to 79*256
#define N_TYPES   5
#define N_EDGES   64000
#define IN_C      2048
#define HID_C     1024
#define OUT_C     512

typedef __attribute__((ext_vector_type(8))) short short8;   // 8 bf16 (4 VGPR)
typedef __attribute__((ext_vector_type(4))) float f32x4;

// ---------------- helpers ----------------
__device__ __forceinline__ unsigned short f2b(float f) {
  union { float f; uint32_t u; } c; c.f = f;
  uint32_t u = c.u;
  u += 0x7FFFu + ((u >> 16) & 1u);          // RNE
  return (unsigned short)(u >> 16);
}
__device__ __forceinline__ float b2f(unsigned short h) {
  union { uint32_t u; float f; } c; c.u = ((uint32_t)h) << 16; return c.f;
}
__device__ __forceinline__ void gload_lds16(const void* g, void* l) {
  __builtin_amdgcn_global_load_lds((__attribute__((address_space(1))) void*)g,
                                   (__attribute__((address_space(3))) void*)l,
                                   16, 0, 0);
}

// ---------------- small prep kernels ----------------
__global__ __launch_bounds__(64) void softmax5_k(const float* __restrict__ attn, float* __restrict__ w) {
  if (threadIdx.x == 0) {
    float m = attn[0];
    for (int i = 1; i < N_TYPES; ++i) m = fmaxf(m, attn[i]);
    float e[N_TYPES], s = 0.f;
    for (int i = 0; i < N_TYPES; ++i) { e[i] = expf(attn[i] - m); s += e[i]; }
    for (int i = 0; i < N_TYPES; ++i) w[i] = e[i] / s;
  }
}

__global__ __launch_bounds__(256) void zero_int_k(int* __restrict__ p, int n) {
  int i = blockIdx.x * 256 + threadIdx.x;
  if (i < n) p[i] = 0;
}

__global__ __launch_bounds__(256) void hist_k(const int* __restrict__ edges, int* __restrict__ deg) {
  int t = blockIdx.x * 256 + threadIdx.x;
  if (t < N_TYPES * N_EDGES) {
    int ty = t / N_EDGES, e = t - ty * N_EDGES;
    int dst = edges[ty * 2 * N_EDGES + N_EDGES + e];
    atomicAdd(&deg[ty * N_NODES + dst], 1);
  }
}

__global__ __launch_bounds__(256) void scan_k(const int* __restrict__ deg, int* __restrict__ rowptr,
                                              int* __restrict__ cursor) {
  int ty = blockIdx.x;
  const int* d = deg + ty * N_NODES;
  int* rp = rowptr + ty * (N_NODES + 1);
  int* cu = cursor + ty * N_NODES;
  __shared__ int sh[256];
  __shared__ int s_carry;
  int tid = threadIdx.x;
  if (tid == 0) s_carry = 0;
  __syncthreads();
  for (int base = 0; base < N_NODES; base += 256) {
    int i = base + tid;
    int v = (i < N_NODES) ? d[i] : 0;
    sh[tid] = v; __syncthreads();
    for (int off = 1; off < 256; off <<= 1) {
      int t2 = (tid >= off) ? sh[tid - off] : 0;
      __syncthreads();
      sh[tid] += t2;
      __syncthreads();
    }
    int incl = sh[tid];
    int c = s_carry;
    if (i < N_NODES) { rp[i] = c + incl - v; cu[i] = c + incl - v; }
    __syncthreads();
    if (tid == 255) s_carry = c + incl;
    __syncthreads();
  }
  if (tid == 0) rp[N_NODES] = s_carry;
}

__global__ __launch_bounds__(256) void scatter_k(const int* __restrict__ edges, int* __restrict__ cursor,
                                                 int* __restrict__ colidx) {
  int t = blockIdx.x * 256 + threadIdx.x;
  if (t < N_TYPES * N_EDGES) {
    int ty = t / N_EDGES, e = t - ty * N_EDGES;
    int src = edges[ty * 2 * N_EDGES + e];
    int dst = edges[ty * 2 * N_EDGES + N_EDGES + e];
    int pos = atomicAdd(&cursor[ty * N_NODES + dst], 1);
    colidx[ty * N_EDGES + pos] = src;
  }
}

// x fp32 [20000,2048] -> bf16 [20224,2048], pad rows zero
__global__ __launch_bounds__(256) void cvt_x_k(const float* __restrict__ x, unsigned short* __restrict__ xb) {
  int i = blockIdx.x * 256 + threadIdx.x;
  int row = i >> 9;
  int c4 = (i & 511) << 2;
  if (row >= MPAD) return;
  ushort4 o;
  if (row < N_NODES) {
    float4 v = *(const float4*)(x + (size_t)row * IN_C + c4);
    o.x = f2b(v.x); o.y = f2b(v.y); o.z = f2b(v.z); o.w = f2b(v.w);
  } else { o.x = 0; o.y = 0; o.z = 0; o.w = 0; }
  *(ushort4*)(xb + (size_t)row * IN_C + c4) = o;
}

// fp32 W [5][C][K] -> bf16 Wcat [5][2C][K], placed at row offset rowoff
__global__ __launch_bounds__(256) void cvt_wcat_k(const float* __restrict__ s,
                                                  unsigned short* __restrict__ d,
                                                  int C, int K4, int rowoff) {
  int i = blockIdx.x * 256 + threadIdx.x;
  int total = N_TYPES * C * K4;
  if (i >= total) return;
  int k4 = i % K4;
  int rr = (i / K4) % C;
  int it = i / (C * K4);
  float4 v = ((const float4*)s)[i];
  ushort4 o; o.x = f2b(v.x); o.y = f2b(v.y); o.z = f2b(v.z); o.w = f2b(v.w);
  ((ushort4*)d)[((size_t)it * 2 * C + rowoff + rr) * K4 + k4] = o;
}

// ---------------- GEMM: PQ[itl] = A[itl] @ Wcat[itl]^T  (all bf16, no bias/relu) ----------------
// 256x256 tile, 8 waves (2Mx4N), BK=32, ring-4 LDS (128 KiB), lookahead-3, vmcnt(8) steady.
// LDS unit layout: [128 LDS-rows][128 B] (two K32 tile-rows per LDS-row);
// swizzle phys = logical ^ ((ldsrow&7)<<4) -> 0 bank conflicts (verified round 4).
// Staging keeps LDS dest linear (global_load_lds); global SOURCE per-lane permuted (inverse map).
template<int NSIZE, int KSIZE>
__global__ __launch_bounds__(512, 2) void gemm_k(
    const unsigned short* __restrict__ Abase, size_t aS,     // per-itl stride (0 = shared A)
    const unsigned short* __restrict__ Wbase,                // [itl][NSIZE][KSIZE] (group-offset)
    unsigned short* __restrict__ PQ) {                       // [itl][MPAD][NSIZE]
  constexpr int NT = KSIZE / 32;
  constexpr int MT = MPAD / 256;
  constexpr int NB = NSIZE / 256;
  __shared__ unsigned short As[4][8192];
  __shared__ unsigned short Bs[4][8192];
  const int tid = threadIdx.x;
  const int lane = tid & 63;
  const int wave = tid >> 6;
  const int wm = wave >> 2, wn = wave & 3;

  // XCD-chunked bijective swizzle (m204), column-fastest within type
  const int nwg = gridDim.x;
  const int flat = blockIdx.x;
  const int q8 = nwg >> 3, r8 = nwg & 7;
  const int xcd = flat & 7, idx = flat >> 3;
  const int wg = (xcd < r8) ? (xcd * (q8 + 1) + idx) : (r8 * (q8 + 1) + (xcd - r8) * q8 + idx);
  const int itl = wg / (MT * NB);
  const int rem = wg % (MT * NB);
  const int row0 = (rem / NB) * 256;
  const int col0 = (rem % NB) * 256;

  const unsigned short* A = Abase + (size_t)itl * aS;
  const unsigned short* W = Wbase + (size_t)itl * NSIZE * KSIZE;

  // staging lane constants (inverse of read swizzle)
  const int sR = lane >> 3;
  const int su = (lane & 7) ^ (sR & 7);
  const int srow = 2 * sR + (su >> 2);
  const int selem = (su & 3) * 8;

  // fragment read byte offsets
  const int fr = lane & 15, k16 = lane >> 4;
  int aoff[8], boff[4];
#pragma unroll
  for (int m = 0; m < 8; ++m) {
    int r = wm * 128 + m * 16 + fr;
    aoff[m] = (((r >> 1) << 7) + ((r & 1) << 6) + (k16 << 4)) ^ (((r >> 1) & 7) << 4);
  }
#pragma unroll
  for (int n = 0; n < 4; ++n) {
    int r = wn * 64 + n * 16 + fr;
    boff[n] = (((r >> 1) << 7) + ((r & 1) << 6) + (k16 << 4)) ^ (((r >> 1) & 7) << 4);
  }

  auto stageA = [&](int t) {
    int s = t & 3; int kb = t * 32;
#pragma unroll
    for (int j = 0; j < 2; ++j) {
      int reg = wave + 8 * j;
      gload_lds16(A + (size_t)(row0 + reg * 16 + srow) * KSIZE + kb + selem, &As[s][reg * 512]);
    }
  };
  auto stageB = [&](int t) {
    int s = t & 3; int kb = t * 32;
#pragma unroll
    for (int j = 0; j < 2; ++j) {
      int reg = wave + 8 * j;
      gload_lds16(W + (size_t)(col0 + reg * 16 + srow) * KSIZE + kb + selem, &Bs[s][reg * 512]);
    }
  };

  f32x4 acc[8][4];
#pragma unroll
  for (int m = 0; m < 8; ++m)
#pragma unroll
    for (int n = 0; n < 4; ++n) acc[m][n] = (f32x4)(0.f);

  stageA(0); stageB(0);
  stageA(1); stageB(1);
  stageA(2); stageB(2);

  for (int t = 0; t < NT; ++t) {
    if (t < NT - 2)       asm volatile("s_waitcnt vmcnt(8)" ::: "memory");
    else if (t == NT - 2) asm volatile("s_waitcnt vmcnt(4)" ::: "memory");
    else                  asm volatile("s_waitcnt vmcnt(0)" ::: "memory");
    __builtin_amdgcn_s_barrier();
    __builtin_amdgcn_sched_barrier(0);
    const int slot = t & 3;
    const char* pa = (const char*)As[slot];
    const char* pb = (const char*)Bs[slot];
    short8 bf[4];
#pragma unroll
    for (int n = 0; n < 4; ++n) bf[n] = *(const short8*)(pb + boff[n]);
    short8 af[4];
#pragma unroll
    for (int m = 0; m < 4; ++m) af[m] = *(const short8*)(pa + aoff[m]);
    if (t + 3 < NT) stageA(t + 3);
    __builtin_amdgcn_s_setprio(1);
#pragma unroll
    for (int m = 0; m < 4; ++m)
#pragma unroll
      for (int n = 0; n < 4; ++n)
        acc[m][n] = __builtin_amdgcn_mfma_f32_16x16x32_bf16(af[m], bf[n], acc[m][n], 0, 0, 0);
    __builtin_amdgcn_s_setprio(0);
    __builtin_amdgcn_s_barrier();
    __builtin_amdgcn_sched_barrier(0);
#pragma unroll
    for (int m = 0; m < 4; ++m) af[m] = *(const short8*)(pa + aoff[m + 4]);
    if (t + 3 < NT) stageB(t + 3);
    __builtin_amdgcn_s_setprio(1);
#pragma unroll
    for (int m = 0; m < 4; ++m)
#pragma unroll
      for (int n = 0; n < 4; ++n)
        acc[m + 4][n] = __builtin_amdgcn_mfma_f32_16x16x32_bf16(af[m], bf[n], acc[m + 4][n], 0, 0, 0);
    __builtin_amdgcn_s_setprio(0);
  }

  // epilogue: D layout col=lane&15, row=(lane>>4)*4+reg
  const int erow = (lane >> 4) * 4;
  const int ecol = lane & 15;
  unsigned short* Op = PQ + (size_t)itl * MPAD * NSIZE;
#pragma unroll
  for (int m = 0; m < 8; ++m) {
#pragma unroll
    for (int n = 0; n < 4; ++n) {
      int gcol = col0 + wn * 64 + n * 16 + ecol;
#pragma unroll
      for (int r = 0; r < 4; ++r) {
        int grow = row0 + wm * 128 + m * 16 + erow + r;
        Op[(size_t)grow * NSIZE + gcol] = f2b(acc[m][n][r]);
      }
    }
  }
}

// ---------------- combine L1/L2: h' = relu(mean_gather(P) + bl + Q); pad rows zeroed ----------------
// PQ [nb][MPAD][2C]: cols [0,C)=P, [C,2C)=Q.  grid = nb*MPAD, 256 thr (C=1024: 4 bf16/thr)
__global__ __launch_bounds__(256) void combine12_k(const unsigned short* __restrict__ PQ,
                                                   unsigned short* __restrict__ Hn,
                                                   const float* __restrict__ bl,
                                                   const int* __restrict__ rowptr,
                                                   const int* __restrict__ colidx, int it0) {
  constexpr int C = HID_C;
  int itl = blockIdx.x / MPAD;
  int node = blockIdx.x % MPAD;
  int it = it0 + itl;
  int tid = threadIdx.x;
  unsigned short* hp = Hn + ((size_t)itl * MPAD + node) * C + tid * 4;
  if (node >= N_NODES) {
    ushort4 z; z.x = 0; z.y = 0; z.z = 0; z.w = 0;
    *(ushort4*)hp = z;
    return;
  }
  const unsigned short* Pb = PQ + (size_t)itl * MPAD * 2 * C;
  const int* rp = rowptr + (size_t)it * (N_NODES + 1);
  const int* ci = colidx + (size_t)it * N_EDGES;
  int beg = rp[node], end = rp[node + 1];
  float a0 = 0.f, a1 = 0.f, a2 = 0.f, a3 = 0.f;
  for (int e = beg; e < end; ++e) {
    int src = ci[e];
    ushort4 u = *(const ushort4*)(Pb + (size_t)src * 2 * C + tid * 4);
    a0 += b2f(u.x); a1 += b2f(u.y); a2 += b2f(u.z); a3 += b2f(u.w);
  }
  float inv = (end > beg) ? 1.f / (float)(end - beg) : 0.f;
  a0 *= inv; a1 *= inv; a2 *= inv; a3 *= inv;
  ushort4 qv = *(const ushort4*)(Pb + (size_t)node * 2 * C + C + tid * 4);
  float4 bv = *(const float4*)(bl + (size_t)it * C + tid * 4);
  ushort4 o;
  o.x = f2b(fmaxf(a0 + b2f(qv.x) + bv.x, 0.f));
  o.y = f2b(fmaxf(a1 + b2f(qv.y) + bv.y, 0.f));
  o.z = f2b(fmaxf(a2 + b2f(qv.z) + bv.z, 0.f));
  o.w = f2b(fmaxf(a3 + b2f(qv.w) + bv.w, 0.f));
  *(ushort4*)hp = o;
}

// ---------------- combine L3: out(+)= sum_it w[it]*(mean_gather(P3) + bl3 + Q3) ----------------
// PQ3 [nb][MPAD][1024]: cols [0,512)=P3, [512,1024)=Q3.  grid = N_NODES, 128 thr x float4
__global__ __launch_bounds__(128) void combine3_k(const unsigned short* __restrict__ PQ,
                                                  const float* __restrict__ bl3,
                                                  const float* __restrict__ wsm,
                                                  const int* __restrict__ rowptr,
                                                  const int* __restrict__ colidx,
                                                  float* __restrict__ out, int it0, int nb, int acc) {
  int node = blockIdx.x;
  int tid = threadIdx.x;
  float s0 = 0.f, s1 = 0.f, s2 = 0.f, s3 = 0.f;
  for (int itl = 0; itl < nb; ++itl) {
    int it = it0 + itl;
    const unsigned short* Pb = PQ + (size_t)itl * MPAD * 1024;
    const int* rp = rowptr + (size_t)it * (N_NODES + 1);
    const int* ci = colidx + (size_t)it * N_EDGES;
    int beg = rp[node], end = rp[node + 1];
    float a0 = 0.f, a1 = 0.f, a2 = 0.f, a3 = 0.f;
    for (int e = beg; e < end; ++e) {
      int src = ci[e];
      ushort4 u = *(const ushort4*)(Pb + (size_t)src * 1024 + tid * 4);
      a0 += b2f(u.x); a1 += b2f(u.y); a2 += b2f(u.z); a3 += b2f(u.w);
    }
    float inv = (end > beg) ? 1.f / (float)(end - beg) : 0.f;
    ushort4 qv = *(const ushort4*)(Pb + (size_t)node * 1024 + 512 + tid * 4);
    float4 bv = *(const float4*)(bl3 + (size_t)it * OUT_C + tid * 4);
    float w = wsm[it];
    s0 += w * (a0 * inv + b2f(qv.x) + bv.x);
    s1 += w * (a1 * inv + b2f(qv.y) + bv.y);
    s2 += w * (a2 * inv + b2f(qv.z) + bv.z);
    s3 += w * (a3 * inv + b2f(qv.w) + bv.w);
  }
  float* op = out + (size_t)node * OUT_C + tid * 4;
  float4 cur = *(float4*)op;
  float4 nv;
  if (acc) { nv.x = cur.x + s0; nv.y = cur.y + s1; nv.z = cur.z + s2; nv.w = cur.w + s3; }
  else     { nv.x = s0; nv.y = s1; nv.z = s2; nv.w = s3; }
  *(float4*)op = nv;
}

// ---------------- final row L2 normalize (in place on d_out) ----------------
__global__ __launch_bounds__(128) void l2norm_k(float* __restrict__ out) {
  int row = blockIdx.x;
  int tid = threadIdx.x;
  float4 v = ((float4*)(out + (size_t)row * OUT_C))[tid];
  float ss = v.x * v.x + v.y * v.y + v.z * v.z + v.w * v.w;
  for (int off = 32; off > 0; off >>= 1) ss += __shfl_down(ss, off);
  __shared__ float s2[2];
  if ((tid & 63) == 0) s2[tid >> 6] = ss;
  __syncthreads();
  float tot = s2[0] + s2[1];
  float inv = 1.f / fmaxf(sqrtf(tot), 1e-12f);
  v.x *= inv; v.y *= inv; v.z *= inv; v.w *= inv;
  ((float4*)(out + (size_t)row * OUT_C))[tid] = v;
}

// ---------------- launch ----------------
extern "C" void kernel_launch(void* const* d_in, const int* in_sizes, int n_in,
                              void* d_out, int out_size, void* d_ws, size_t ws_size,
                              hipStream_t stream) {
  const float* x    = (const float*)d_in[0];
  const int*   edges = (const int*)d_in[1];
  const float* Wl1 = (const float*)d_in[2];
  const float* bl1 = (const float*)d_in[3];
  const float* Wr1 = (const float*)d_in[4];
  const float* Wl2 = (const float*)d_in[5];
  const float* bl2 = (const float*)d_in[6];
  const float* Wr2 = (const float*)d_in[7];
  const float* Wl3 = (const float*)d_in[8];
  const float* bl3 = (const float*)d_in[9];
  const float* Wr3 = (const float*)d_in[10];
  const float* attn = (const float*)d_in[11];
  float* out = (float*)d_out;

  char* ws = (char*)d_ws;
  size_t off = 0;
  auto alloc = [&](size_t bytes) -> char* {
    char* p = ws + off;
    off = (off + bytes + 255) & ~(size_t)255;
    return p;
  };
  float* wsm   = (float*)alloc(N_TYPES * 4);
  int* deg     = (int*)alloc((size_t)N_TYPES * N_NODES * 4);
  int* rowptr  = (int*)alloc((size_t)N_TYPES * (N_NODES + 1) * 4);
  int* cursor  = (int*)alloc((size_t)N_TYPES * N_NODES * 4);
  int* colidx  = (int*)alloc((size_t)N_TYPES * N_EDGES * 4);
  unsigned short* xb    = (unsigned short*)alloc((size_t)MPAD * IN_C * 2);
  unsigned short* wcat1 = (unsigned short*)alloc((size_t)N_TYPES * 2 * HID_C * IN_C * 2);
  unsigned short* wcat2 = (unsigned short*)alloc((size_t)N_TYPES * 2 * HID_C * HID_C * 2);
  unsigned short* wcat3 = (unsigned short*)alloc((size_t)N_TYPES * 2 * OUT_C * HID_C * 2);
  size_t persist = off;

  // pick largest type-batch nb that fits: need = persist + nb*(PQ 2C + h C) slabs
  const size_t pqSlab = (size_t)MPAD * 2 * HID_C * 2;   // 82.9 MB
  const size_t hSlab  = (size_t)MPAD * HID_C * 2;       // 41.4 MB
  int nb = 1;
  for (int c = N_TYPES; c >= 1; --c) {
    size_t need = persist + (size_t)c * (pqSlab + hSlab) + 4096;
    if (need <= ws_size) { nb = c; break; }
  }
  unsigned short* PQ   = (unsigned short*)alloc((size_t)nb * pqSlab);
  unsigned short* hbuf = (unsigned short*)alloc((size_t)nb * hSlab);

  // prep
  softmax5_k<<<1, 64, 0, stream>>>(attn, wsm);
  zero_int_k<<<(N_TYPES * N_NODES + 255) / 256, 256, 0, stream>>>(deg, N_TYPES * N_NODES);
  hist_k<<<(N_TYPES * N_EDGES + 255) / 256, 256, 0, stream>>>(edges, deg);
  scan_k<<<N_TYPES, 256, 0, stream>>>(deg, rowptr, cursor);
  scatter_k<<<(N_TYPES * N_EDGES + 255) / 256, 256, 0, stream>>>(edges, cursor, colidx);

  cvt_x_k<<<((size_t)MPAD * IN_C / 4 + 255) / 256, 256, 0, stream>>>(x, xb);
  {
    int t1 = N_TYPES * HID_C * (IN_C / 4);
    cvt_wcat_k<<<(t1 + 255) / 256, 256, 0, stream>>>(Wl1, wcat1, HID_C, IN_C / 4, 0);
    cvt_wcat_k<<<(t1 + 255) / 256, 256, 0, stream>>>(Wr1, wcat1, HID_C, IN_C / 4, HID_C);
    int t2 = N_TYPES * HID_C * (HID_C / 4);
    cvt_wcat_k<<<(t2 + 255) / 256, 256, 0, stream>>>(Wl2, wcat2, HID_C, HID_C / 4, 0);
    cvt_wcat_k<<<(t2 + 255) / 256, 256, 0, stream>>>(Wr2, wcat2, HID_C, HID_C / 4, HID_C);
    int t3 = N_TYPES * OUT_C * (HID_C / 4);
    cvt_wcat_k<<<(t3 + 255) / 256, 256, 0, stream>>>(Wl3, wcat3, OUT_C, HID_C / 4, 0);
    cvt_wcat_k<<<(t3 + 255) / 256, 256, 0, stream>>>(Wr3, wcat3, OUT_C, HID_C / 4, OUT_C);
  }

  const int MT = MPAD / 256;
  for (int g0 = 0; g0 < N_TYPES; g0 += nb) {
    int nbg = (N_TYPES - g0 < nb) ? (N_TYPES - g0) : nb;
    // layer 1: PQ = x @ [Wl1;Wr1]^T   (A shared across types: stride 0)
    gemm_k<2 * HID_C, IN_C><<<nbg * MT * (2 * HID_C / 256), 512, 0, stream>>>(
        xb, 0, wcat1 + (size_t)g0 * 2 * HID_C * IN_C, PQ);
    combine12_k<<<nbg * MPAD, 256, 0, stream>>>(PQ, hbuf, bl1, rowptr, colidx, g0);
    // layer 2: PQ = h1 @ [Wl2;Wr2]^T
    gemm_k<2 * HID_C, HID_C><<<nbg * MT * (2 * HID_C / 256), 512, 0, stream>>>(
        hbuf, hSlab / 2, wcat2 + (size_t)g0 * 2 * HID_C * HID_C, PQ);
    combine12_k<<<nbg * MPAD, 256, 0, stream>>>(PQ, hbuf, bl2, rowptr, colidx, g0);
    // layer 3: PQ3 = h2 @ [Wl3;Wr3]^T  (N=1024)
    gemm_k<2 * OUT_C, HID_C><<<nbg * MT * (2 * OUT_C / 256), 512, 0, stream>>>(
        hbuf, hSlab / 2, wcat3 + (size_t)g0 * 2 * OUT_C * HID_C, PQ);
    combine3_k<<<N_NODES, 128, 0, stream>>>(PQ, bl3, wsm, rowptr, colidx, out, g0, nbg,
                                            (g0 > 0) ? 1 : 0);
  }

  l2norm_k<<<N_NODES, 128, 0, stream>>>(out);
}

// Round 6
// 2208.898 us; speedup vs baseline: 1.7560x; 1.0438x over previous
//
#include <hip/hip_runtime.h>
#include <hip/hip_bf16.h>
#include <stdint.h>

// ---------------- constants ----------------
#define N_NODES   20000
#define MPAD      20224          // padded to 79*256
#define N_TYPES   5
#define N_EDGES   64000
#define IN_C      2048
#define HID_C     1024
#define OUT_C     512

typedef __attribute__((ext_vector_type(8))) short short8;   // 8 bf16 (4 VGPR)
typedef __attribute__((ext_vector_type(4))) float f32x4;

// ---------------- helpers ----------------
__device__ __forceinline__ unsigned short f2b(float f) {
  union { float f; uint32_t u; } c; c.f = f;
  uint32_t u = c.u;
  u += 0x7FFFu + ((u >> 16) & 1u);          // RNE
  return (unsigned short)(u >> 16);
}
__device__ __forceinline__ float b2f(unsigned short h) {
  union { uint32_t u; float f; } c; c.u = ((uint32_t)h) << 16; return c.f;
}
__device__ __forceinline__ void gload_lds16(const void* g, void* l) {
  __builtin_amdgcn_global_load_lds((__attribute__((address_space(1))) void*)g,
                                   (__attribute__((address_space(3))) void*)l,
                                   16, 0, 0);
}

// ---------------- small prep kernels ----------------
__global__ __launch_bounds__(64) void softmax5_k(const float* __restrict__ attn, float* __restrict__ w) {
  if (threadIdx.x == 0) {
    float m = attn[0];
    for (int i = 1; i < N_TYPES; ++i) m = fmaxf(m, attn[i]);
    float e[N_TYPES], s = 0.f;
    for (int i = 0; i < N_TYPES; ++i) { e[i] = expf(attn[i] - m); s += e[i]; }
    for (int i = 0; i < N_TYPES; ++i) w[i] = e[i] / s;
  }
}

__global__ __launch_bounds__(256) void zero_int_k(int* __restrict__ p, int n) {
  int i = blockIdx.x * 256 + threadIdx.x;
  if (i < n) p[i] = 0;
}

__global__ __launch_bounds__(256) void hist_k(const int* __restrict__ edges, int* __restrict__ deg) {
  int t = blockIdx.x * 256 + threadIdx.x;
  if (t < N_TYPES * N_EDGES) {
    int ty = t / N_EDGES, e = t - ty * N_EDGES;
    int dst = edges[ty * 2 * N_EDGES + N_EDGES + e];
    atomicAdd(&deg[ty * N_NODES + dst], 1);
  }
}

__global__ __launch_bounds__(256) void scan_k(const int* __restrict__ deg, int* __restrict__ rowptr,
                                              int* __restrict__ cursor) {
  int ty = blockIdx.x;
  const int* d = deg + ty * N_NODES;
  int* rp = rowptr + ty * (N_NODES + 1);
  int* cu = cursor + ty * N_NODES;
  __shared__ int sh[256];
  __shared__ int s_carry;
  int tid = threadIdx.x;
  if (tid == 0) s_carry = 0;
  __syncthreads();
  for (int base = 0; base < N_NODES; base += 256) {
    int i = base + tid;
    int v = (i < N_NODES) ? d[i] : 0;
    sh[tid] = v; __syncthreads();
    for (int off = 1; off < 256; off <<= 1) {
      int t2 = (tid >= off) ? sh[tid - off] : 0;
      __syncthreads();
      sh[tid] += t2;
      __syncthreads();
    }
    int incl = sh[tid];
    int c = s_carry;
    if (i < N_NODES) { rp[i] = c + incl - v; cu[i] = c + incl - v; }
    __syncthreads();
    if (tid == 255) s_carry = c + incl;
    __syncthreads();
  }
  if (tid == 0) rp[N_NODES] = s_carry;
}

__global__ __launch_bounds__(256) void scatter_k(const int* __restrict__ edges, int* __restrict__ cursor,
                                                 int* __restrict__ colidx) {
  int t = blockIdx.x * 256 + threadIdx.x;
  if (t < N_TYPES * N_EDGES) {
    int ty = t / N_EDGES, e = t - ty * N_EDGES;
    int src = edges[ty * 2 * N_EDGES + e];
    int dst = edges[ty * 2 * N_EDGES + N_EDGES + e];
    int pos = atomicAdd(&cursor[ty * N_NODES + dst], 1);
    colidx[ty * N_EDGES + pos] = src;
  }
}

// x fp32 [20000,2048] -> bf16 [20224,2048], pad rows zero
__global__ __launch_bounds__(256) void cvt_x_k(const float* __restrict__ x, unsigned short* __restrict__ xb) {
  int i = blockIdx.x * 256 + threadIdx.x;
  int row = i >> 9;
  int c4 = (i & 511) << 2;
  if (row >= MPAD) return;
  ushort4 o;
  if (row < N_NODES) {
    float4 v = *(const float4*)(x + (size_t)row * IN_C + c4);
    o.x = f2b(v.x); o.y = f2b(v.y); o.z = f2b(v.z); o.w = f2b(v.w);
  } else { o.x = 0; o.y = 0; o.z = 0; o.w = 0; }
  *(ushort4*)(xb + (size_t)row * IN_C + c4) = o;
}

// fp32 W [5][C][K] -> bf16 Wcat [5][2C][K], placed at row offset rowoff
__global__ __launch_bounds__(256) void cvt_wcat_k(const float* __restrict__ s,
                                                  unsigned short* __restrict__ d,
                                                  int C, int K4, int rowoff) {
  int i = blockIdx.x * 256 + threadIdx.x;
  int total = N_TYPES * C * K4;
  if (i >= total) return;
  int k4 = i % K4;
  int rr = (i / K4) % C;
  int it = i / (C * K4);
  float4 v = ((const float4*)s)[i];
  ushort4 o; o.x = f2b(v.x); o.y = f2b(v.y); o.z = f2b(v.z); o.w = f2b(v.w);
  ((ushort4*)d)[((size_t)it * 2 * C + rowoff + rr) * K4 + k4] = o;
}

// ---------------- GEMM: PQ[itl] = A[itl] @ Wcat[itl]^T  (all bf16, no bias/relu) ----------------
// 256x256 tile, 8 waves (2Mx4N), BK=32, ring-4 LDS (128 KiB), lookahead-3, vmcnt(8) steady.
// LDS unit layout: [128 LDS-rows][128 B] (two K32 tile-rows per LDS-row);
// swizzle phys = logical ^ ((ldsrow&7)<<4) -> 0 bank conflicts (verified round 4).
// Staging keeps LDS dest linear (global_load_lds); global SOURCE per-lane permuted (inverse map).
// Round-6 change: ALL 16 per-tile ds_reads hoisted to tile top (after the single
// vmcnt+barrier) and mid-tile barrier removed -> A-high read latency + 2nd wave's
// reads hide under the MFMA-lo cluster (compiler emits fine-grained lgkmcnt).
// Stage-slot safety needs only the TOP barrier: slot (t+3)&3 = (t-1)&3, whose
// reads all completed before any wave passed this tile's top barrier.
template<int NSIZE, int KSIZE>
__global__ __launch_bounds__(512, 2) void gemm_k(
    const unsigned short* __restrict__ Abase, size_t aS,     // per-itl stride (0 = shared A)
    const unsigned short* __restrict__ Wbase,                // [itl][NSIZE][KSIZE] (group-offset)
    unsigned short* __restrict__ PQ) {                       // [itl][MPAD][NSIZE]
  constexpr int NT = KSIZE / 32;
  constexpr int MT = MPAD / 256;
  constexpr int NB = NSIZE / 256;
  __shared__ unsigned short As[4][8192];
  __shared__ unsigned short Bs[4][8192];
  const int tid = threadIdx.x;
  const int lane = tid & 63;
  const int wave = tid >> 6;
  const int wm = wave >> 2, wn = wave & 3;

  // XCD-chunked bijective swizzle (m204), column-fastest within type
  const int nwg = gridDim.x;
  const int flat = blockIdx.x;
  const int q8 = nwg >> 3, r8 = nwg & 7;
  const int xcd = flat & 7, idx = flat >> 3;
  const int wg = (xcd < r8) ? (xcd * (q8 + 1) + idx) : (r8 * (q8 + 1) + (xcd - r8) * q8 + idx);
  const int itl = wg / (MT * NB);
  const int rem = wg % (MT * NB);
  const int row0 = (rem / NB) * 256;
  const int col0 = (rem % NB) * 256;

  const unsigned short* A = Abase + (size_t)itl * aS;
  const unsigned short* W = Wbase + (size_t)itl * NSIZE * KSIZE;

  // staging lane constants (inverse of read swizzle)
  const int sR = lane >> 3;
  const int su = (lane & 7) ^ (sR & 7);
  const int srow = 2 * sR + (su >> 2);
  const int selem = (su & 3) * 8;

  // fragment read byte offsets
  const int fr = lane & 15, k16 = lane >> 4;
  int aoff[8], boff[4];
#pragma unroll
  for (int m = 0; m < 8; ++m) {
    int r = wm * 128 + m * 16 + fr;
    aoff[m] = (((r >> 1) << 7) + ((r & 1) << 6) + (k16 << 4)) ^ (((r >> 1) & 7) << 4);
  }
#pragma unroll
  for (int n = 0; n < 4; ++n) {
    int r = wn * 64 + n * 16 + fr;
    boff[n] = (((r >> 1) << 7) + ((r & 1) << 6) + (k16 << 4)) ^ (((r >> 1) & 7) << 4);
  }

  auto stageA = [&](int t) {
    int s = t & 3; int kb = t * 32;
#pragma unroll
    for (int j = 0; j < 2; ++j) {
      int reg = wave + 8 * j;
      gload_lds16(A + (size_t)(row0 + reg * 16 + srow) * KSIZE + kb + selem, &As[s][reg * 512]);
    }
  };
  auto stageB = [&](int t) {
    int s = t & 3; int kb = t * 32;
#pragma unroll
    for (int j = 0; j < 2; ++j) {
      int reg = wave + 8 * j;
      gload_lds16(W + (size_t)(col0 + reg * 16 + srow) * KSIZE + kb + selem, &Bs[s][reg * 512]);
    }
  };

  f32x4 acc[8][4];
#pragma unroll
  for (int m = 0; m < 8; ++m)
#pragma unroll
    for (int n = 0; n < 4; ++n) acc[m][n] = (f32x4)(0.f);

  stageA(0); stageB(0);
  stageA(1); stageB(1);
  stageA(2); stageB(2);

  for (int t = 0; t < NT; ++t) {
    if (t < NT - 2)       asm volatile("s_waitcnt vmcnt(8)" ::: "memory");
    else if (t == NT - 2) asm volatile("s_waitcnt vmcnt(4)" ::: "memory");
    else                  asm volatile("s_waitcnt vmcnt(0)" ::: "memory");
    __builtin_amdgcn_s_barrier();
    __builtin_amdgcn_sched_barrier(0);
    const int slot = t & 3;
    const char* pa = (const char*)As[slot];
    const char* pb = (const char*)Bs[slot];
    // all 16 per-tile ds_reads issued up front; lgkm waits interleave with MFMA-lo
    short8 bf[4], af[8];
#pragma unroll
    for (int n = 0; n < 4; ++n) bf[n] = *(const short8*)(pb + boff[n]);
#pragma unroll
    for (int m = 0; m < 8; ++m) af[m] = *(const short8*)(pa + aoff[m]);
    if (t + 3 < NT) stageA(t + 3);
    __builtin_amdgcn_s_setprio(1);
#pragma unroll
    for (int m = 0; m < 4; ++m)
#pragma unroll
      for (int n = 0; n < 4; ++n)
        acc[m][n] = __builtin_amdgcn_mfma_f32_16x16x32_bf16(af[m], bf[n], acc[m][n], 0, 0, 0);
    __builtin_amdgcn_s_setprio(0);
    if (t + 3 < NT) stageB(t + 3);
    __builtin_amdgcn_s_setprio(1);
#pragma unroll
    for (int m = 0; m < 4; ++m)
#pragma unroll
      for (int n = 0; n < 4; ++n)
        acc[m + 4][n] = __builtin_amdgcn_mfma_f32_16x16x32_bf16(af[m + 4], bf[n], acc[m + 4][n], 0, 0, 0);
    __builtin_amdgcn_s_setprio(0);
  }

  // epilogue: D layout col=lane&15, row=(lane>>4)*4+reg
  const int erow = (lane >> 4) * 4;
  const int ecol = lane & 15;
  unsigned short* Op = PQ + (size_t)itl * MPAD * NSIZE;
#pragma unroll
  for (int m = 0; m < 8; ++m) {
#pragma unroll
    for (int n = 0; n < 4; ++n) {
      int gcol = col0 + wn * 64 + n * 16 + ecol;
#pragma unroll
      for (int r = 0; r < 4; ++r) {
        int grow = row0 + wm * 128 + m * 16 + erow + r;
        Op[(size_t)grow * NSIZE + gcol] = f2b(acc[m][n][r]);
      }
    }
  }
}

// ---------------- combine L1/L2: h' = relu(mean_gather(P) + bl + Q); pad rows zeroed ----------------
// PQ [nb][MPAD][2C]: cols [0,C)=P, [C,2C)=Q.  grid = nb*MPAD, 256 thr (C=1024: 4 bf16/thr)
__global__ __launch_bounds__(256) void combine12_k(const unsigned short* __restrict__ PQ,
                                                   unsigned short* __restrict__ Hn,
                                                   const float* __restrict__ bl,
                                                   const int* __restrict__ rowptr,
                                                   const int* __restrict__ colidx, int it0) {
  constexpr int C = HID_C;
  int itl = blockIdx.x / MPAD;
  int node = blockIdx.x % MPAD;
  int it = it0 + itl;
  int tid = threadIdx.x;
  unsigned short* hp = Hn + ((size_t)itl * MPAD + node) * C + tid * 4;
  if (node >= N_NODES) {
    ushort4 z; z.x = 0; z.y = 0; z.z = 0; z.w = 0;
    *(ushort4*)hp = z;
    return;
  }
  const unsigned short* Pb = PQ + (size_t)itl * MPAD * 2 * C;
  const int* rp = rowptr + (size_t)it * (N_NODES + 1);
  const int* ci = colidx + (size_t)it * N_EDGES;
  int beg = rp[node], end = rp[node + 1];
  float a0 = 0.f, a1 = 0.f, a2 = 0.f, a3 = 0.f;
  for (int e = beg; e < end; ++e) {
    int src = ci[e];
    ushort4 u = *(const ushort4*)(Pb + (size_t)src * 2 * C + tid * 4);
    a0 += b2f(u.x); a1 += b2f(u.y); a2 += b2f(u.z); a3 += b2f(u.w);
  }
  float inv = (end > beg) ? 1.f / (float)(end - beg) : 0.f;
  a0 *= inv; a1 *= inv; a2 *= inv; a3 *= inv;
  ushort4 qv = *(const ushort4*)(Pb + (size_t)node * 2 * C + C + tid * 4);
  float4 bv = *(const float4*)(bl + (size_t)it * C + tid * 4);
  ushort4 o;
  o.x = f2b(fmaxf(a0 + b2f(qv.x) + bv.x, 0.f));
  o.y = f2b(fmaxf(a1 + b2f(qv.y) + bv.y, 0.f));
  o.z = f2b(fmaxf(a2 + b2f(qv.z) + bv.z, 0.f));
  o.w = f2b(fmaxf(a3 + b2f(qv.w) + bv.w, 0.f));
  *(ushort4*)hp = o;
}

// ---------------- combine L3: out(+)= sum_it w[it]*(mean_gather(P3) + bl3 + Q3) ----------------
// PQ3 [nb][MPAD][1024]: cols [0,512)=P3, [512,1024)=Q3.  grid = N_NODES, 128 thr x float4
__global__ __launch_bounds__(128) void combine3_k(const unsigned short* __restrict__ PQ,
                                                  const float* __restrict__ bl3,
                                                  const float* __restrict__ wsm,
                                                  const int* __restrict__ rowptr,
                                                  const int* __restrict__ colidx,
                                                  float* __restrict__ out, int it0, int nb, int acc) {
  int node = blockIdx.x;
  int tid = threadIdx.x;
  float s0 = 0.f, s1 = 0.f, s2 = 0.f, s3 = 0.f;
  for (int itl = 0; itl < nb; ++itl) {
    int it = it0 + itl;
    const unsigned short* Pb = PQ + (size_t)itl * MPAD * 1024;
    const int* rp = rowptr + (size_t)it * (N_NODES + 1);
    const int* ci = colidx + (size_t)it * N_EDGES;
    int beg = rp[node], end = rp[node + 1];
    float a0 = 0.f, a1 = 0.f, a2 = 0.f, a3 = 0.f;
    for (int e = beg; e < end; ++e) {
      int src = ci[e];
      ushort4 u = *(const ushort4*)(Pb + (size_t)src * 1024 + tid * 4);
      a0 += b2f(u.x); a1 += b2f(u.y); a2 += b2f(u.z); a3 += b2f(u.w);
    }
    float inv = (end > beg) ? 1.f / (float)(end - beg) : 0.f;
    ushort4 qv = *(const ushort4*)(Pb + (size_t)node * 1024 + 512 + tid * 4);
    float4 bv = *(const float4*)(bl3 + (size_t)it * OUT_C + tid * 4);
    float w = wsm[it];
    s0 += w * (a0 * inv + b2f(qv.x) + bv.x);
    s1 += w * (a1 * inv + b2f(qv.y) + bv.y);
    s2 += w * (a2 * inv + b2f(qv.z) + bv.z);
    s3 += w * (a3 * inv + b2f(qv.w) + bv.w);
  }
  float* op = out + (size_t)node * OUT_C + tid * 4;
  float4 cur = *(float4*)op;
  float4 nv;
  if (acc) { nv.x = cur.x + s0; nv.y = cur.y + s1; nv.z = cur.z + s2; nv.w = cur.w + s3; }
  else     { nv.x = s0; nv.y = s1; nv.z = s2; nv.w = s3; }
  *(float4*)op = nv;
}

// ---------------- final row L2 normalize (in place on d_out) ----------------
__global__ __launch_bounds__(128) void l2norm_k(float* __restrict__ out) {
  int row = blockIdx.x;
  int tid = threadIdx.x;
  float4 v = ((float4*)(out + (size_t)row * OUT_C))[tid];
  float ss = v.x * v.x + v.y * v.y + v.z * v.z + v.w * v.w;
  for (int off = 32; off > 0; off >>= 1) ss += __shfl_down(ss, off);
  __shared__ float s2[2];
  if ((tid & 63) == 0) s2[tid >> 6] = ss;
  __syncthreads();
  float tot = s2[0] + s2[1];
  float inv = 1.f / fmaxf(sqrtf(tot), 1e-12f);
  v.x *= inv; v.y *= inv; v.z *= inv; v.w *= inv;
  ((float4*)(out + (size_t)row * OUT_C))[tid] = v;
}

// ---------------- launch ----------------
extern "C" void kernel_launch(void* const* d_in, const int* in_sizes, int n_in,
                              void* d_out, int out_size, void* d_ws, size_t ws_size,
                              hipStream_t stream) {
  const float* x    = (const float*)d_in[0];
  const int*   edges = (const int*)d_in[1];
  const float* Wl1 = (const float*)d_in[2];
  const float* bl1 = (const float*)d_in[3];
  const float* Wr1 = (const float*)d_in[4];
  const float* Wl2 = (const float*)d_in[5];
  const float* bl2 = (const float*)d_in[6];
  const float* Wr2 = (const float*)d_in[7];
  const float* Wl3 = (const float*)d_in[8];
  const float* bl3 = (const float*)d_in[9];
  const float* Wr3 = (const float*)d_in[10];
  const float* attn = (const float*)d_in[11];
  float* out = (float*)d_out;

  char* ws = (char*)d_ws;
  size_t off = 0;
  auto alloc = [&](size_t bytes) -> char* {
    char* p = ws + off;
    off = (off + bytes + 255) & ~(size_t)255;
    return p;
  };
  float* wsm   = (float*)alloc(N_TYPES * 4);
  int* deg     = (int*)alloc((size_t)N_TYPES * N_NODES * 4);
  int* rowptr  = (int*)alloc((size_t)N_TYPES * (N_NODES + 1) * 4);
  int* cursor  = (int*)alloc((size_t)N_TYPES * N_NODES * 4);
  int* colidx  = (int*)alloc((size_t)N_TYPES * N_EDGES * 4);
  unsigned short* xb    = (unsigned short*)alloc((size_t)MPAD * IN_C * 2);
  unsigned short* wcat1 = (unsigned short*)alloc((size_t)N_TYPES * 2 * HID_C * IN_C * 2);
  unsigned short* wcat2 = (unsigned short*)alloc((size_t)N_TYPES * 2 * HID_C * HID_C * 2);
  unsigned short* wcat3 = (unsigned short*)alloc((size_t)N_TYPES * 2 * OUT_C * HID_C * 2);
  size_t persist = off;

  // pick largest type-batch nb that fits: need = persist + nb*(PQ 2C + h C) slabs
  const size_t pqSlab = (size_t)MPAD * 2 * HID_C * 2;   // 82.9 MB
  const size_t hSlab  = (size_t)MPAD * HID_C * 2;       // 41.4 MB
  int nb = 1;
  for (int c = N_TYPES; c >= 1; --c) {
    size_t need = persist + (size_t)c * (pqSlab + hSlab) + 4096;
    if (need <= ws_size) { nb = c; break; }
  }
  unsigned short* PQ   = (unsigned short*)alloc((size_t)nb * pqSlab);
  unsigned short* hbuf = (unsigned short*)alloc((size_t)nb * hSlab);

  // prep
  softmax5_k<<<1, 64, 0, stream>>>(attn, wsm);
  zero_int_k<<<(N_TYPES * N_NODES + 255) / 256, 256, 0, stream>>>(deg, N_TYPES * N_NODES);
  hist_k<<<(N_TYPES * N_EDGES + 255) / 256, 256, 0, stream>>>(edges, deg);
  scan_k<<<N_TYPES, 256, 0, stream>>>(deg, rowptr, cursor);
  scatter_k<<<(N_TYPES * N_EDGES + 255) / 256, 256, 0, stream>>>(edges, cursor, colidx);

  cvt_x_k<<<((size_t)MPAD * IN_C / 4 + 255) / 256, 256, 0, stream>>>(x, xb);
  {
    int t1 = N_TYPES * HID_C * (IN_C / 4);
    cvt_wcat_k<<<(t1 + 255) / 256, 256, 0, stream>>>(Wl1, wcat1, HID_C, IN_C / 4, 0);
    cvt_wcat_k<<<(t1 + 255) / 256, 256, 0, stream>>>(Wr1, wcat1, HID_C, IN_C / 4, HID_C);
    int t2 = N_TYPES * HID_C * (HID_C / 4);
    cvt_wcat_k<<<(t2 + 255) / 256, 256, 0, stream>>>(Wl2, wcat2, HID_C, HID_C / 4, 0);
    cvt_wcat_k<<<(t2 + 255) / 256, 256, 0, stream>>>(Wr2, wcat2, HID_C, HID_C / 4, HID_C);
    int t3 = N_TYPES * OUT_C * (HID_C / 4);
    cvt_wcat_k<<<(t3 + 255) / 256, 256, 0, stream>>>(Wl3, wcat3, OUT_C, HID_C / 4, 0);
    cvt_wcat_k<<<(t3 + 255) / 256, 256, 0, stream>>>(Wr3, wcat3, OUT_C, HID_C / 4, OUT_C);
  }

  const int MT = MPAD / 256;
  for (int g0 = 0; g0 < N_TYPES; g0 += nb) {
    int nbg = (N_TYPES - g0 < nb) ? (N_TYPES - g0) : nb;
    // layer 1: PQ = x @ [Wl1;Wr1]^T   (A shared across types: stride 0)
    gemm_k<2 * HID_C, IN_C><<<nbg * MT * (2 * HID_C / 256), 512, 0, stream>>>(
        xb, 0, wcat1 + (size_t)g0 * 2 * HID_C * IN_C, PQ);
    combine12_k<<<nbg * MPAD, 256, 0, stream>>>(PQ, hbuf, bl1, rowptr, colidx, g0);
    // layer 2: PQ = h1 @ [Wl2;Wr2]^T
    gemm_k<2 * HID_C, HID_C><<<nbg * MT * (2 * HID_C / 256), 512, 0, stream>>>(
        hbuf, hSlab / 2, wcat2 + (size_t)g0 * 2 * HID_C * HID_C, PQ);
    combine12_k<<<nbg * MPAD, 256, 0, stream>>>(PQ, hbuf, bl2, rowptr, colidx, g0);
    // layer 3: PQ3 = h2 @ [Wl3;Wr3]^T  (N=1024)
    gemm_k<2 * OUT_C, HID_C><<<nbg * MT * (2 * OUT_C / 256), 512, 0, stream>>>(
        hbuf, hSlab / 2, wcat3 + (size_t)g0 * 2 * OUT_C * HID_C, PQ);
    combine3_k<<<N_NODES, 128, 0, stream>>>(PQ, bl3, wsm, rowptr, colidx, out, g0, nbg,
                                            (g0 > 0) ? 1 : 0);
  }

  l2norm_k<<<N_NODES, 128, 0, stream>>>(out);
}